// Round 1
// baseline (2405.203 us; speedup 1.0000x reference)
//
#include <hip/hip_runtime.h>
#include <hip/hip_bf16.h>

#define DIM 128
#define NHEAD 4

typedef __attribute__((ext_vector_type(8))) short bf16x8;
typedef __attribute__((ext_vector_type(4))) float f32x4;

__device__ __forceinline__ unsigned short f2bf(float f) {
    unsigned u = __float_as_uint(f);
    unsigned r = (u + 0x7FFFu + ((u >> 16) & 1u)) >> 16;  // RNE
    return (unsigned short)r;
}
__device__ __forceinline__ float bf2f(unsigned short b) {
    return __uint_as_float(((unsigned)b) << 16);
}

__device__ __forceinline__ void atomicMaxF(float* addr, float v) {
    if (v >= 0.f) atomicMax((int*)addr, __float_as_int(v));
    else          atomicMin((unsigned int*)addr, (unsigned int)__float_as_int(v));
}

// ---------------------------------------------------------------------------
// Generic  out[M x 128] = op( A[M x 128] @ W[128 x 128] + bias + res )
// A: fp32 or bf16 (IN_BF16). out: fp32 or bf16 (OUT_BF16). RELU optional.
// bias/res may be null. res is fp32 [M x 128].
// Tile: 64 rows x 128 cols per block, 256 threads (4 waves, 2x2 wave grid),
// mfma_f32_16x16x32_bf16, K-loop of 4.
// ---------------------------------------------------------------------------
template<bool IN_BF16, bool OUT_BF16, bool RELU>
__global__ __launch_bounds__(256) void gemm128(
    const void* __restrict__ Av, const float* __restrict__ W,
    const float* __restrict__ bias, const float* __restrict__ res,
    void* __restrict__ Ov, int M)
{
    // +8 bf16 pad per row: breaks the D=128 32-way bank conflict (G4)
    __shared__ __align__(16) unsigned short As[64][136];
    __shared__ __align__(16) unsigned short Ws[128][136];  // W transposed: Ws[n][k]

    const int t = threadIdx.x;
    const int row0 = blockIdx.x * 64;

    // stage W (transposed) -> LDS, bf16
    for (int idx = t; idx < 128 * 128; idx += 256) {
        int i = idx >> 7, j = idx & 127;
        Ws[j][i] = f2bf(W[idx]);
    }
    // stage A tile -> LDS, bf16
    if (IN_BF16) {
        const unsigned short* A = (const unsigned short*)Av;
        for (int base = t * 8; base < 64 * 128; base += 256 * 8) {
            int r = base >> 7, c = base & 127;
            long row = row0 + r;
            uint4 d;
            if (row < M) d = *reinterpret_cast<const uint4*>(A + row * 128 + c);
            else         d = make_uint4(0u, 0u, 0u, 0u);
            *reinterpret_cast<uint4*>(&As[r][c]) = d;
        }
    } else {
        const float* A = (const float*)Av;
        for (int base = t * 4; base < 64 * 128; base += 256 * 4) {
            int r = base >> 7, c = base & 127;
            long row = row0 + r;
            float4 d;
            if (row < M) d = *reinterpret_cast<const float4*>(A + row * 128 + c);
            else         d = make_float4(0.f, 0.f, 0.f, 0.f);
            As[r][c + 0] = f2bf(d.x); As[r][c + 1] = f2bf(d.y);
            As[r][c + 2] = f2bf(d.z); As[r][c + 3] = f2bf(d.w);
        }
    }
    __syncthreads();

    const int wave = t >> 6, lane = t & 63;
    const int wm = wave >> 1, wn = wave & 1;     // wave tile: 32 rows x 64 cols
    const int lr = lane & 15, lk = lane >> 4;

    f32x4 acc[2][4];
#pragma unroll
    for (int a = 0; a < 2; a++)
#pragma unroll
        for (int b = 0; b < 4; b++) acc[a][b] = (f32x4){0.f, 0.f, 0.f, 0.f};

#pragma unroll
    for (int kk = 0; kk < 4; kk++) {
        const int k0 = kk * 32 + lk * 8;
        bf16x8 af[2], bfr[4];
#pragma unroll
        for (int fm = 0; fm < 2; fm++)
            af[fm] = *reinterpret_cast<const bf16x8*>(&As[wm * 32 + fm * 16 + lr][k0]);
#pragma unroll
        for (int fn = 0; fn < 4; fn++)
            bfr[fn] = *reinterpret_cast<const bf16x8*>(&Ws[wn * 64 + fn * 16 + lr][k0]);
#pragma unroll
        for (int fm = 0; fm < 2; fm++)
#pragma unroll
            for (int fn = 0; fn < 4; fn++)
                acc[fm][fn] = __builtin_amdgcn_mfma_f32_16x16x32_bf16(
                    af[fm], bfr[fn], acc[fm][fn], 0, 0, 0);
    }

    // epilogue: C/D layout col = lane&15, row = (lane>>4)*4 + reg  [m89-verified]
#pragma unroll
    for (int fm = 0; fm < 2; fm++) {
#pragma unroll
        for (int fn = 0; fn < 4; fn++) {
            const int col = wn * 64 + fn * 16 + lr;
#pragma unroll
            for (int r = 0; r < 4; r++) {
                const int rl = wm * 32 + fm * 16 + lk * 4 + r;
                const long row = row0 + rl;
                if (row < M) {
                    float v = acc[fm][fn][r];
                    if (bias) v += bias[col];
                    if (res)  v += res[row * 128 + col];
                    if (RELU) v = fmaxf(v, 0.f);
                    if (OUT_BF16) ((unsigned short*)Ov)[row * 128 + col] = f2bf(v);
                    else          ((float*)Ov)[row * 128 + col] = v;
                }
            }
        }
    }
}

// ---------------------------------------------------------------------------
__global__ void cvt_f32_bf16(const float* __restrict__ in, unsigned short* __restrict__ out, long n4) {
    long i = (long)blockIdx.x * 256 + threadIdx.x;
    if (i >= n4) return;
    float4 v = reinterpret_cast<const float4*>(in)[i];
    ushort4 o;
    o.x = f2bf(v.x); o.y = f2bf(v.y); o.z = f2bf(v.z); o.w = f2bf(v.w);
    reinterpret_cast<ushort4*>(out)[i] = o;
}

__global__ void init_attn(float* __restrict__ smax, float* __restrict__ denom,
                          float* __restrict__ ctx, int N_) {
    int i = blockIdx.x * 256 + threadIdx.x;
    if (i < N_ * NHEAD) { smax[i] = -3.0e38f; denom[i] = 0.f; }
    if (i < N_ * DIM) ctx[i] = 0.f;
}

// scores[e][h] = (q[dst[e],h,:] . k[e,h,:]) / sqrt(32);  atomicMax into smax
__global__ __launch_bounds__(256) void scores_kernel(
    const float* __restrict__ q, const unsigned short* __restrict__ k,
    const int* __restrict__ dst, float* __restrict__ scores,
    float* __restrict__ smax, int E)
{
    int t = threadIdx.x;
    int e = blockIdx.x * 2 + (t >> 7);
    if (e >= E) return;
    int d = t & 127;
    int n = dst[e];
    float val = q[(long)n * 128 + d] * bf2f(k[(long)e * 128 + d]);
#pragma unroll
    for (int off = 16; off >= 1; off >>= 1) val += __shfl_xor(val, off, 64);
    if ((t & 31) == 0) {
        int head = d >> 5;
        float s = val * 0.17677669529663687f;  // 1/sqrt(32)
        scores[(long)e * 4 + head] = s;
        atomicMaxF(&smax[n * 4 + head], s);
    }
}

// p = exp(s - smax[dst]); ctx[dst] += p*v; denom[dst] += p
__global__ __launch_bounds__(256) void pv_kernel(
    const float* __restrict__ scores, const float* __restrict__ smax,
    const unsigned short* __restrict__ v, const int* __restrict__ dst,
    float* __restrict__ ctx, float* __restrict__ denom, int E)
{
    int t = threadIdx.x;
    int e = blockIdx.x * 2 + (t >> 7);
    if (e >= E) return;
    int d = t & 127;
    int n = dst[e];
    int head = d >> 5;
    float pr = __expf(scores[(long)e * 4 + head] - smax[n * 4 + head]);
    atomicAdd(&ctx[(long)n * 128 + d], pr * bf2f(v[(long)e * 128 + d]));
    if ((d & 31) == 0) atomicAdd(&denom[n * 4 + head], pr);
}

__global__ void norm_ctx(float* __restrict__ ctx, const float* __restrict__ denom, int N_) {
    int i = blockIdx.x * 256 + threadIdx.x;
    if (i >= N_ * DIM) return;
    int n = i >> 7, head = (i & 127) >> 5;
    ctx[i] /= denom[n * 4 + head];
}

// m[e] = f_h[src[e]] - h[e^1]   (bf16 out)
__global__ void make_m(const float* __restrict__ f_h, const unsigned short* __restrict__ h,
                       const int* __restrict__ src, unsigned short* __restrict__ m, long total) {
    long i = (long)blockIdx.x * 256 + threadIdx.x;
    if (i >= total) return;
    int e = (int)(i >> 7);
    int d = (int)(i & 127);
    float val = f_h[(long)src[e] * 128 + d] - bf2f(h[i ^ 128]);  // e^1 == flip bit7 of flat idx
    m[i] = f2bf(val);
}

__global__ void mail_kernel(const unsigned short* __restrict__ h, const int* __restrict__ dst,
                            float* __restrict__ mail, long total) {
    long i = (long)blockIdx.x * 256 + threadIdx.x;
    if (i >= total) return;
    int e = (int)(i >> 7);
    int d = (int)(i & 127);
    atomicAdd(&mail[(long)dst[e] * 128 + d], bf2f(h[i]));
}

// ---------------------------------------------------------------------------
extern "C" void kernel_launch(void* const* d_in, const int* in_sizes, int n_in,
                              void* d_out, int out_size, void* d_ws, size_t ws_size,
                              hipStream_t stream)
{
    const float* f      = (const float*)d_in[0];
    const float* x      = (const float*)d_in[1];
    const int*   src    = (const int*)d_in[2];
    const int*   dst    = (const int*)d_in[3];
    const float* Wq     = (const float*)d_in[4];
    const float* bq     = (const float*)d_in[5];
    const float* Wk     = (const float*)d_in[6];
    const float* bk     = (const float*)d_in[7];
    const float* Wv     = (const float*)d_in[8];
    const float* bv     = (const float*)d_in[9];
    const float* Wo     = (const float*)d_in[10];
    const float* bo     = (const float*)d_in[11];
    const float* W_mp   = (const float*)d_in[12];
    const float* b_mp   = (const float*)d_in[13];
    const float* W_last = (const float*)d_in[14];
    const float* b_last = (const float*)d_in[15];

    const int N = in_sizes[0] / 128;
    const int E = in_sizes[1] / 128;

    char* p = (char*)d_ws;
    auto take = [&](size_t bytes) { char* r = p; p += (bytes + 255) & ~(size_t)255; return r; };
    unsigned short* h0 = (unsigned short*)take((size_t)E * 128 * 2);
    unsigned short* h1 = (unsigned short*)take((size_t)E * 128 * 2);
    unsigned short* kb = (unsigned short*)take((size_t)E * 128 * 2);  // k, then reused as m
    unsigned short* vb = (unsigned short*)take((size_t)E * 128 * 2);
    float* f_h    = (float*)take((size_t)N * 128 * 4);
    float* q      = (float*)take((size_t)N * 128 * 4);
    float* ctx    = (float*)take((size_t)N * 128 * 4);  // reused as mail at the end
    float* scores = (float*)take((size_t)E * 4 * 4);
    float* smax   = (float*)take((size_t)N * 4 * 4);
    float* denom  = (float*)take((size_t)N * 4 * 4);

    // h = bf16(x); f_h = f
    {
        long n4 = (long)E * 128 / 4;
        cvt_f32_bf16<<<(int)((n4 + 255) / 256), 256, 0, stream>>>(x, h0, n4);
    }
    hipMemcpyAsync(f_h, f, (size_t)N * 128 * 4, hipMemcpyDeviceToDevice, stream);

    unsigned short* hc = h0;
    unsigned short* hn = h1;
    const int gN = (N + 63) / 64;
    const int gE = (E + 63) / 64;
    const long etot = (long)E * 128;

    for (int it = 0; it < 2; it++) {
        // q = f_h @ Wq + bq
        gemm128<false, false, false><<<gN, 256, 0, stream>>>(f_h, Wq, bq, nullptr, q, N);
        init_attn<<<(N * 128 + 255) / 256, 256, 0, stream>>>(smax, denom, ctx, N);
        // k, v = h @ Wk/Wv + b   (bf16 out)
        gemm128<true, true, false><<<gE, 256, 0, stream>>>(hc, Wk, bk, nullptr, kb, E);
        gemm128<true, true, false><<<gE, 256, 0, stream>>>(hc, Wv, bv, nullptr, vb, E);
        // segment softmax over dst
        scores_kernel<<<(E + 1) / 2, 256, 0, stream>>>(q, kb, dst, scores, smax, E);
        pv_kernel<<<(E + 1) / 2, 256, 0, stream>>>(scores, smax, vb, dst, ctx, denom, E);
        norm_ctx<<<(N * 128 + 255) / 256, 256, 0, stream>>>(ctx, denom, N);
        // f_h = ctx @ Wo + bo + f_h   (residual, in-place safe: elementwise)
        gemm128<false, false, false><<<gN, 256, 0, stream>>>(ctx, Wo, bo, f_h, f_h, N);
        // m = f_h[src] - rev(h)  (into kb);  h' = relu(x + m @ W_mp[it] + b_mp[it])
        make_m<<<(int)((etot + 255) / 256), 256, 0, stream>>>(f_h, hc, src, kb, etot);
        gemm128<true, true, true><<<gE, 256, 0, stream>>>(
            kb, W_mp + (size_t)it * 128 * 128, b_mp + (size_t)it * 128, x, hn, E);
        unsigned short* tmp = hc; hc = hn; hn = tmp;
    }

    // mail = segment_sum(h, dst)
    hipMemsetAsync(ctx, 0, (size_t)N * 128 * 4, stream);
    mail_kernel<<<(int)((etot + 255) / 256), 256, 0, stream>>>(hc, dst, ctx, etot);

    // out = [mail, f_h, f] @ W_last + b_last   (three K=128 chunks, accumulated)
    gemm128<false, false, false><<<gN, 256, 0, stream>>>(ctx, W_last, b_last, nullptr, (float*)d_out, N);
    gemm128<false, false, false><<<gN, 256, 0, stream>>>(f_h, W_last + 128 * 128, nullptr, (float*)d_out, (float*)d_out, N);
    gemm128<false, false, false><<<gN, 256, 0, stream>>>(f, W_last + 256 * 128, nullptr, (float*)d_out, (float*)d_out, N);
}

// Round 2
// 1759.606 us; speedup vs baseline: 1.3669x; 1.3669x over previous
//
#include <hip/hip_runtime.h>
#include <hip/hip_bf16.h>

typedef __attribute__((ext_vector_type(8))) short bf16x8;
typedef __attribute__((ext_vector_type(4))) float f32x4;

__device__ __forceinline__ unsigned short f2bf(float f) {
    unsigned u = __float_as_uint(f);
    unsigned r = (u + 0x7FFFu + ((u >> 16) & 1u)) >> 16;  // RNE
    return (unsigned short)r;
}
__device__ __forceinline__ float bf2f(unsigned short b) {
    return __uint_as_float(((unsigned)b) << 16);
}

__device__ __forceinline__ void atomicMaxF(float* addr, float v) {
    if (v >= 0.f) atomicMax((int*)addr, __float_as_int(v));
    else          atomicMin((unsigned int*)addr, (unsigned int)__float_as_int(v));
}

// async global->LDS, 16B per lane; dest = wave-uniform base + lane*16 (m104)
__device__ __forceinline__ void gload_lds16(const void* g, void* l) {
    __builtin_amdgcn_global_load_lds(
        (const __attribute__((address_space(1))) unsigned int*)g,
        (__attribute__((address_space(3))) unsigned int*)l,
        16, 0, 0);
}

// ---------------------------------------------------------------------------
// Single-W GEMM: out[M x 128] = op(A[M x 128](bf16) @ W + bias + res)
// W given pre-transposed bf16: WT[n][k]. B-panel lives in VGPRs (64/wave).
// 128-row tiles, persistent blocks, dbuf LDS, global_load_lds w/ XOR swizzle.
// RES: 0 none, 1 fp32, 2 bf16. 4 waves: wave w -> rows (w>>1)*64, cols (w&1)*64.
// ---------------------------------------------------------------------------
template<bool RELU, int RES, bool OUT_BF16>
__global__ __launch_bounds__(256, 2) void gemm_s(
    const unsigned short* __restrict__ A, const unsigned short* __restrict__ WT,
    const float* __restrict__ bias, const void* res,
    void* out, int M, int ntiles)
{
    __shared__ __align__(16) unsigned short As[2][128 * 128];  // 2 x 32KB

    const int t = threadIdx.x, wave = t >> 6, lane = t & 63;
    const int lr = lane & 15, lk = lane >> 4;
    const int wm = wave >> 1, wn = wave & 1;

    // B panel -> registers (once per block)
    bf16x8 Bf[4][4];  // [kk][fn]
    float bs[4];
#pragma unroll
    for (int fn = 0; fn < 4; fn++) {
        const int n = wn * 64 + fn * 16 + lr;
        bs[fn] = bias ? bias[n] : 0.f;
#pragma unroll
        for (int kk = 0; kk < 4; kk++)
            Bf[kk][fn] = *reinterpret_cast<const bf16x8*>(WT + n * 128 + kk * 32 + lk * 8);
    }

    auto stage = [&](int buf, int row0) {
#pragma unroll
        for (int i = 0; i < 8; i++) {
            const int flat = (wave * 8 + i) * 1024 + lane * 16;  // byte in 32KB tile
            const int r = flat >> 8;                              // row 0..127
            const int c = (flat >> 4) & 15;                       // 16B chunk
            int gr = row0 + r; if (gr >= M) gr = M - 1;
            const void* g = A + (size_t)gr * 128 + ((c ^ (r & 7)) << 3);
            void* l = (void*)((char*)&As[buf][0] + (size_t)(wave * 8 + i) * 1024);
            gload_lds16(g, l);
        }
    };

    int tt = blockIdx.x;
    if (tt >= ntiles) return;
    int cur = 0;
    stage(0, tt * 128);
    __syncthreads();

    for (; tt < ntiles; tt += gridDim.x) {
        const int nxt = tt + gridDim.x;
        if (nxt < ntiles) stage(cur ^ 1, nxt * 128);

        f32x4 acc[4][4];
#pragma unroll
        for (int a = 0; a < 4; a++)
#pragma unroll
            for (int b = 0; b < 4; b++) acc[a][b] = (f32x4){0.f, 0.f, 0.f, 0.f};

#pragma unroll
        for (int kk = 0; kk < 4; kk++) {
            bf16x8 af[4];
#pragma unroll
            for (int fm = 0; fm < 4; fm++) {
                const int r = wm * 64 + fm * 16 + lr;
                const int c = (kk * 4 + lk) ^ (r & 7);
                af[fm] = *reinterpret_cast<const bf16x8*>(&As[cur][r * 128 + c * 8]);
            }
#pragma unroll
            for (int fm = 0; fm < 4; fm++)
#pragma unroll
                for (int fn = 0; fn < 4; fn++)
                    acc[fm][fn] = __builtin_amdgcn_mfma_f32_16x16x32_bf16(
                        af[fm], Bf[kk][fn], acc[fm][fn], 0, 0, 0);
        }

        const int row0 = tt * 128;
#pragma unroll
        for (int fm = 0; fm < 4; fm++) {
#pragma unroll
            for (int fn = 0; fn < 4; fn++) {
                const int col = wn * 64 + fn * 16 + lr;
#pragma unroll
                for (int r4 = 0; r4 < 4; r4++) {
                    const int rl = wm * 64 + fm * 16 + lk * 4 + r4;
                    const int row = row0 + rl;
                    if (row < M) {
                        float v = acc[fm][fn][r4] + bs[fn];
                        const size_t off = (size_t)row * 128 + col;
                        if (RES == 1) v += ((const float*)res)[off];
                        if (RES == 2) v += bf2f(((const unsigned short*)res)[off]);
                        if (RELU) v = fmaxf(v, 0.f);
                        if (OUT_BF16) ((unsigned short*)out)[off] = f2bf(v);
                        else          ((float*)out)[off] = v;
                    }
                }
            }
        }
        __syncthreads();
        cur ^= 1;
    }
}

// ---------------------------------------------------------------------------
// Fused K+V GEMM: waves 0-1 compute K (cols 0-63 / 64-127), waves 2-3 V.
// 64-row tiles; A staged once for both outputs.
// ---------------------------------------------------------------------------
__global__ __launch_bounds__(256, 2) void gemm_kv(
    const unsigned short* __restrict__ A,
    const unsigned short* __restrict__ WkT, const unsigned short* __restrict__ WvT,
    const float* __restrict__ bk, const float* __restrict__ bvv,
    unsigned short* __restrict__ K, unsigned short* __restrict__ V,
    int M, int ntiles)
{
    __shared__ __align__(16) unsigned short As[2][64 * 128];  // 2 x 16KB

    const int t = threadIdx.x, wave = t >> 6, lane = t & 63;
    const int lr = lane & 15, lk = lane >> 4;
    const int wsel = wave >> 1, wn = wave & 1;

    const unsigned short* WT = wsel ? WvT : WkT;
    const float* bias = wsel ? bvv : bk;
    unsigned short* out = wsel ? V : K;

    bf16x8 Bf[4][4];
    float bs[4];
#pragma unroll
    for (int fn = 0; fn < 4; fn++) {
        const int n = wn * 64 + fn * 16 + lr;
        bs[fn] = bias[n];
#pragma unroll
        for (int kk = 0; kk < 4; kk++)
            Bf[kk][fn] = *reinterpret_cast<const bf16x8*>(WT + n * 128 + kk * 32 + lk * 8);
    }

    auto stage = [&](int buf, int row0) {
#pragma unroll
        for (int i = 0; i < 4; i++) {
            const int flat = (wave * 4 + i) * 1024 + lane * 16;
            const int r = flat >> 8;       // 0..63
            const int c = (flat >> 4) & 15;
            int gr = row0 + r; if (gr >= M) gr = M - 1;
            const void* g = A + (size_t)gr * 128 + ((c ^ (r & 7)) << 3);
            void* l = (void*)((char*)&As[buf][0] + (size_t)(wave * 4 + i) * 1024);
            gload_lds16(g, l);
        }
    };

    int tt = blockIdx.x;
    if (tt >= ntiles) return;
    int cur = 0;
    stage(0, tt * 64);
    __syncthreads();

    for (; tt < ntiles; tt += gridDim.x) {
        const int nxt = tt + gridDim.x;
        if (nxt < ntiles) stage(cur ^ 1, nxt * 64);

        f32x4 acc[4][4];
#pragma unroll
        for (int a = 0; a < 4; a++)
#pragma unroll
            for (int b = 0; b < 4; b++) acc[a][b] = (f32x4){0.f, 0.f, 0.f, 0.f};

#pragma unroll
        for (int kk = 0; kk < 4; kk++) {
            bf16x8 af[4];
#pragma unroll
            for (int fm = 0; fm < 4; fm++) {
                const int r = fm * 16 + lr;
                const int c = (kk * 4 + lk) ^ (r & 7);
                af[fm] = *reinterpret_cast<const bf16x8*>(&As[cur][r * 128 + c * 8]);
            }
#pragma unroll
            for (int fm = 0; fm < 4; fm++)
#pragma unroll
                for (int fn = 0; fn < 4; fn++)
                    acc[fm][fn] = __builtin_amdgcn_mfma_f32_16x16x32_bf16(
                        af[fm], Bf[kk][fn], acc[fm][fn], 0, 0, 0);
        }

        const int row0 = tt * 64;
#pragma unroll
        for (int fm = 0; fm < 4; fm++) {
#pragma unroll
            for (int fn = 0; fn < 4; fn++) {
                const int col = wn * 64 + fn * 16 + lr;
#pragma unroll
                for (int r4 = 0; r4 < 4; r4++) {
                    const int rl = fm * 16 + lk * 4 + r4;
                    const int row = row0 + rl;
                    if (row < M)
                        out[(size_t)row * 128 + col] = f2bf(acc[fm][fn][r4] + bs[fn]);
                }
            }
        }
        __syncthreads();
        cur ^= 1;
    }
}

// ---------------------------------------------------------------------------
struct W9 { const float* p[9]; };

// transpose+convert 9 128x128 fp32 weight mats -> bf16 [n][k]
__global__ void cvt_wT(W9 w, unsigned short* __restrict__ out) {
    const float* src = w.p[blockIdx.x];
    unsigned short* dst = out + (size_t)blockIdx.x * 16384;
    for (int idx = threadIdx.x; idx < 16384; idx += 256) {
        const int k = idx >> 7, n = idx & 127;
        dst[n * 128 + k] = f2bf(src[idx]);
    }
}

__global__ void cvt_bf16(const float* __restrict__ in, unsigned short* __restrict__ out, long n4) {
    long i = (long)blockIdx.x * 256 + threadIdx.x;
    if (i >= n4) return;
    float4 v = reinterpret_cast<const float4*>(in)[i];
    ushort4 o;
    o.x = f2bf(v.x); o.y = f2bf(v.y); o.z = f2bf(v.z); o.w = f2bf(v.w);
    reinterpret_cast<ushort4*>(out)[i] = o;
}

// ctxb = bf16(ctx / denom[n,head]) -- fused normalize+convert
__global__ void cvt_ctx(const float* __restrict__ ctx, const float* __restrict__ denom,
                        unsigned short* __restrict__ out, int total4) {
    int i = blockIdx.x * 256 + threadIdx.x;
    if (i >= total4) return;
    const int n = i >> 5, head = (i >> 3) & 3;
    const float rcp = 1.f / denom[n * 4 + head];
    float4 v = reinterpret_cast<const float4*>(ctx)[i];
    ushort4 o;
    o.x = f2bf(v.x * rcp); o.y = f2bf(v.y * rcp);
    o.z = f2bf(v.z * rcp); o.w = f2bf(v.w * rcp);
    reinterpret_cast<ushort4*>(out)[i] = o;
}

__global__ void init_attn(float* __restrict__ smax, float* __restrict__ denom,
                          float* __restrict__ ctx, int N_) {
    int i = blockIdx.x * 256 + threadIdx.x;
    if (i < N_ * 4) { smax[i] = -3.0e38f; denom[i] = 0.f; }
    if (i < N_ * 128) ctx[i] = 0.f;
}

__global__ __launch_bounds__(256) void scores_kernel(
    const float* __restrict__ q, const unsigned short* __restrict__ k,
    const int* __restrict__ dst, float* __restrict__ scores,
    float* __restrict__ smax, int E)
{
    int t = threadIdx.x;
    int e = blockIdx.x * 2 + (t >> 7);
    if (e >= E) return;
    int d = t & 127;
    int n = dst[e];
    float val = q[(long)n * 128 + d] * bf2f(k[(long)e * 128 + d]);
#pragma unroll
    for (int off = 16; off >= 1; off >>= 1) val += __shfl_xor(val, off, 64);
    if ((t & 31) == 0) {
        int head = d >> 5;
        float s = val * 0.17677669529663687f;  // 1/sqrt(32)
        scores[(long)e * 4 + head] = s;
        atomicMaxF(&smax[n * 4 + head], s);
    }
}

__global__ __launch_bounds__(256) void pv_kernel(
    const float* __restrict__ scores, const float* __restrict__ smax,
    const unsigned short* __restrict__ v, const int* __restrict__ dst,
    float* __restrict__ ctx, float* __restrict__ denom, int E)
{
    int t = threadIdx.x;
    int e = blockIdx.x * 2 + (t >> 7);
    if (e >= E) return;
    int d = t & 127;
    int n = dst[e];
    int head = d >> 5;
    float pr = __expf(scores[(long)e * 4 + head] - smax[n * 4 + head]);
    atomicAdd(&ctx[(long)n * 128 + d], pr * bf2f(v[(long)e * 128 + d]));
    if ((d & 31) == 0) atomicAdd(&denom[n * 4 + head], pr);
}

__device__ __forceinline__ unsigned pksub(unsigned a, unsigned b) {
    float r0 = bf2f((unsigned short)(a & 0xffff)) - bf2f((unsigned short)(b & 0xffff));
    float r1 = bf2f((unsigned short)(a >> 16))    - bf2f((unsigned short)(b >> 16));
    return (unsigned)f2bf(r0) | ((unsigned)f2bf(r1) << 16);
}

// m[e] = f_hb[src[e]] - h[e^1], all bf16, 8 elems (16B) per thread
__global__ void make_m(const unsigned short* __restrict__ f_hb, const unsigned short* __restrict__ h,
                       const int* __restrict__ src, unsigned short* __restrict__ m, long nchunks) {
    long i = (long)blockIdx.x * 256 + threadIdx.x;
    if (i >= nchunks) return;
    const long e = i >> 4;
    const int c = (int)(i & 15);
    uint4 hv = reinterpret_cast<const uint4*>(h)[i ^ 16];  // reverse edge: e^1
    uint4 fv = reinterpret_cast<const uint4*>(f_hb)[(long)src[e] * 16 + c];
    uint4 o;
    o.x = pksub(fv.x, hv.x); o.y = pksub(fv.y, hv.y);
    o.z = pksub(fv.z, hv.z); o.w = pksub(fv.w, hv.w);
    reinterpret_cast<uint4*>(m)[i] = o;
}

__global__ void mail_kernel(const unsigned short* __restrict__ h, const int* __restrict__ dst,
                            float* __restrict__ mail, long total) {
    long i = (long)blockIdx.x * 256 + threadIdx.x;
    if (i >= total) return;
    int e = (int)(i >> 7);
    int d = (int)(i & 127);
    atomicAdd(&mail[(long)dst[e] * 128 + d], bf2f(h[i]));
}

// ---------------------------------------------------------------------------
extern "C" void kernel_launch(void* const* d_in, const int* in_sizes, int n_in,
                              void* d_out, int out_size, void* d_ws, size_t ws_size,
                              hipStream_t stream)
{
    const float* f      = (const float*)d_in[0];
    const float* x      = (const float*)d_in[1];
    const int*   src    = (const int*)d_in[2];
    const int*   dst    = (const int*)d_in[3];
    const float* Wq     = (const float*)d_in[4];
    const float* bq     = (const float*)d_in[5];
    const float* Wk     = (const float*)d_in[6];
    const float* bk     = (const float*)d_in[7];
    const float* Wv     = (const float*)d_in[8];
    const float* bv     = (const float*)d_in[9];
    const float* Wo     = (const float*)d_in[10];
    const float* bo     = (const float*)d_in[11];
    const float* W_mp   = (const float*)d_in[12];
    const float* b_mp   = (const float*)d_in[13];
    const float* W_last = (const float*)d_in[14];
    const float* b_last = (const float*)d_in[15];

    const int N = in_sizes[0] / 128;
    const int E = in_sizes[1] / 128;

    char* p = (char*)d_ws;
    auto take = [&](size_t bytes) { char* r = p; p += (bytes + 255) & ~(size_t)255; return r; };
    unsigned short* w9T  = (unsigned short*)take(9 * 16384 * 2);
    unsigned short* xb   = (unsigned short*)take((size_t)E * 128 * 2);
    unsigned short* h1   = (unsigned short*)take((size_t)E * 128 * 2);
    unsigned short* kb   = (unsigned short*)take((size_t)E * 128 * 2);  // k, reused as m
    unsigned short* vb   = (unsigned short*)take((size_t)E * 128 * 2);
    unsigned short* fb   = (unsigned short*)take((size_t)N * 128 * 2);
    unsigned short* f_hb = (unsigned short*)take((size_t)N * 128 * 2);
    float* f_h    = (float*)take((size_t)N * 128 * 4);
    float* q      = (float*)take((size_t)N * 128 * 4);   // reused as ctxb/mailb
    float* ctx    = (float*)take((size_t)N * 128 * 4);   // reused as mail
    float* scores = (float*)take((size_t)E * 4 * 4);
    float* smax   = (float*)take((size_t)N * 4 * 4);
    float* denom  = (float*)take((size_t)N * 4 * 4);
    unsigned short* ctxb = (unsigned short*)q;

    const unsigned short* WqT  = w9T + 0 * 16384;
    const unsigned short* WkT  = w9T + 1 * 16384;
    const unsigned short* WvT  = w9T + 2 * 16384;
    const unsigned short* WoT  = w9T + 3 * 16384;
    const unsigned short* Wm0T = w9T + 4 * 16384;
    const unsigned short* Wm1T = w9T + 5 * 16384;
    const unsigned short* WL0T = w9T + 6 * 16384;
    const unsigned short* WL1T = w9T + 7 * 16384;
    const unsigned short* WL2T = w9T + 8 * 16384;

    W9 w9;
    w9.p[0] = Wq; w9.p[1] = Wk; w9.p[2] = Wv; w9.p[3] = Wo;
    w9.p[4] = W_mp; w9.p[5] = W_mp + 16384;
    w9.p[6] = W_last; w9.p[7] = W_last + 16384; w9.p[8] = W_last + 32768;

    cvt_wT<<<9, 256, 0, stream>>>(w9, w9T);
    {
        long n4 = (long)E * 32;
        cvt_bf16<<<(int)((n4 + 255) / 256), 256, 0, stream>>>(x, xb, n4);
        long m4 = (long)N * 32;
        cvt_bf16<<<(int)((m4 + 255) / 256), 256, 0, stream>>>(f, fb, m4);
    }
    hipMemcpyAsync(f_h, f, (size_t)N * 128 * 4, hipMemcpyDeviceToDevice, stream);

    const int ntN = (N + 127) / 128;
    const int ntE128 = (E + 127) / 128;
    const int ntE64 = (E + 63) / 64;
    const long mchunks = (long)E * 16;

    const unsigned short* hc = xb;   // h starts as x
    for (int it = 0; it < 2; it++) {
        const unsigned short* fh_in = (it == 0) ? fb : f_hb;
        // q = f_h @ Wq + bq  (fp32 out)
        gemm_s<false, 0, false><<<ntN, 256, 0, stream>>>(fh_in, WqT, bq, nullptr, q, N, ntN);
        init_attn<<<(N * 128 + 255) / 256, 256, 0, stream>>>(smax, denom, ctx, N);
        // k,v fused
        gemm_kv<<<625, 256, 0, stream>>>(hc, WkT, WvT, bk, bv, kb, vb, E, ntE64);
        // segment softmax
        scores_kernel<<<(E + 1) / 2, 256, 0, stream>>>(q, kb, dst, scores, smax, E);
        pv_kernel<<<(E + 1) / 2, 256, 0, stream>>>(scores, smax, vb, dst, ctx, denom, E);
        // ctxb = bf16(ctx/denom)  [q is dead now; ctxb aliases q]
        cvt_ctx<<<(N * 32 + 255) / 256, 256, 0, stream>>>(ctx, denom, ctxb, N * 32);
        // f_h = ctxb @ Wo + bo + f_h
        gemm_s<false, 1, false><<<ntN, 256, 0, stream>>>(ctxb, WoT, bo, f_h, f_h, N, ntN);
        // f_hb = bf16(f_h)
        cvt_bf16<<<(N * 32 + 255) / 256, 256, 0, stream>>>(f_h, f_hb, (long)N * 32);
        // m = f_hb[src] - rev(h)  -> kb
        make_m<<<(int)((mchunks + 255) / 256), 256, 0, stream>>>(f_hb, hc, src, kb, mchunks);
        // h' = relu(x + m @ W_mp[it] + b_mp[it]) -> h1 (in-place safe on iter 1)
        gemm_s<true, 2, true><<<625, 256, 0, stream>>>(
            kb, (it == 0) ? Wm0T : Wm1T, b_mp + (size_t)it * 128, xb, h1, E, ntE128);
        hc = h1;
    }

    // mail = segment_sum(h, dst) -> ctx
    hipMemsetAsync(ctx, 0, (size_t)N * 128 * 4, stream);
    mail_kernel<<<(int)(((long)E * 128 + 255) / 256), 256, 0, stream>>>(hc, dst, ctx, (long)E * 128);
    // mailb = bf16(mail)  [ctxb buffer reused]
    cvt_bf16<<<(N * 32 + 255) / 256, 256, 0, stream>>>(ctx, ctxb, (long)N * 32);

    // out = mail@WL0 + f_h@WL1 + f@WL2 + b_last  (three accumulating passes)
    gemm_s<false, 0, false><<<ntN, 256, 0, stream>>>(ctxb, WL0T, b_last, nullptr, (float*)d_out, N, ntN);
    gemm_s<false, 1, false><<<ntN, 256, 0, stream>>>(f_hb, WL1T, nullptr, d_out, (float*)d_out, N, ntN);
    gemm_s<false, 1, false><<<ntN, 256, 0, stream>>>(fb, WL2T, nullptr, d_out, (float*)d_out, N, ntN);
}

// Round 3
// 919.633 us; speedup vs baseline: 2.6154x; 1.9134x over previous
//
#include <hip/hip_runtime.h>
#include <hip/hip_bf16.h>

typedef __attribute__((ext_vector_type(8))) short bf16x8;
typedef __attribute__((ext_vector_type(4))) float f32x4;

__device__ __forceinline__ unsigned short f2bf(float f) {
    unsigned u = __float_as_uint(f);
    unsigned r = (u + 0x7FFFu + ((u >> 16) & 1u)) >> 16;  // RNE
    return (unsigned short)r;
}
__device__ __forceinline__ float bf2f(unsigned short b) {
    return __uint_as_float(((unsigned)b) << 16);
}
__device__ __forceinline__ unsigned pack2(float a, float b) {
    return (unsigned)f2bf(a) | ((unsigned)f2bf(b) << 16);
}

// async global->LDS, 16B per lane; dest = wave-uniform base + lane*16 (m104)
__device__ __forceinline__ void gload_lds16(const void* g, void* l) {
    __builtin_amdgcn_global_load_lds(
        (const __attribute__((address_space(1))) unsigned int*)g,
        (__attribute__((address_space(3))) unsigned int*)l,
        16, 0, 0);
}

// ---------------------------------------------------------------------------
// out[M x 128] = op(A[M x 128](bf16) @ W + bias + res)
// WT: pre-transposed bf16 W[n][k]. B-panel in VGPRs. Swapped-operand MFMA:
// mfma(Bf, af) -> lane holds 4 consecutive COLS at fixed row -> 8B/16B stores.
// RES: 0 none, 1 fp32, 2 bf16. OUT2: also emit bf16 copy.
// ---------------------------------------------------------------------------
template<bool RELU, int RES, bool OUT_BF16, bool OUT2>
__global__ __launch_bounds__(256, 2) void gemm_s(
    const unsigned short* __restrict__ A, const unsigned short* __restrict__ WT,
    const float* __restrict__ bias, const void* res,
    void* out, unsigned short* __restrict__ out2, int M, int ntiles)
{
    __shared__ __align__(16) unsigned short As[2][128 * 128];  // 2 x 32KB

    const int t = threadIdx.x, wave = t >> 6, lane = t & 63;
    const int lr = lane & 15, lk = lane >> 4;
    const int wm = wave >> 1, wn = wave & 1;

    // B panel + bias -> registers (once per block)
    bf16x8 Bf[4][4];  // [kk][fn]
    f32x4 bs[4];
#pragma unroll
    for (int fn = 0; fn < 4; fn++) {
        const int col0 = wn * 64 + fn * 16 + lk * 4;
        bs[fn] = bias ? *reinterpret_cast<const f32x4*>(bias + col0)
                      : (f32x4){0.f, 0.f, 0.f, 0.f};
        const int n = wn * 64 + fn * 16 + lr;
#pragma unroll
        for (int kk = 0; kk < 4; kk++)
            Bf[kk][fn] = *reinterpret_cast<const bf16x8*>(WT + n * 128 + kk * 32 + lk * 8);
    }

    auto stage = [&](int buf, int row0) {
#pragma unroll
        for (int i = 0; i < 8; i++) {
            const int flat = (wave * 8 + i) * 1024 + lane * 16;  // byte in 32KB tile
            const int r = flat >> 8;                              // row 0..127
            const int c = (flat >> 4) & 15;                       // 16B chunk
            int gr = row0 + r; if (gr >= M) gr = M - 1;
            const void* g = A + (size_t)gr * 128 + ((c ^ (r & 7)) << 3);
            void* l = (void*)((char*)&As[buf][0] + (size_t)(wave * 8 + i) * 1024);
            gload_lds16(g, l);
        }
    };

    int tt = blockIdx.x;
    if (tt >= ntiles) return;
    int cur = 0;
    stage(0, tt * 128);
    __syncthreads();

    for (; tt < ntiles; tt += gridDim.x) {
        const int nxt = tt + gridDim.x;
        if (nxt < ntiles) stage(cur ^ 1, nxt * 128);

        f32x4 acc[4][4];
#pragma unroll
        for (int a = 0; a < 4; a++)
#pragma unroll
            for (int b = 0; b < 4; b++) acc[a][b] = (f32x4){0.f, 0.f, 0.f, 0.f};

#pragma unroll
        for (int kk = 0; kk < 4; kk++) {
            bf16x8 af[4];
#pragma unroll
            for (int fm = 0; fm < 4; fm++) {
                const int r = wm * 64 + fm * 16 + lr;
                const int c = (kk * 4 + lk) ^ (r & 7);
                af[fm] = *reinterpret_cast<const bf16x8*>(&As[cur][r * 128 + c * 8]);
            }
#pragma unroll
            for (int fm = 0; fm < 4; fm++)
#pragma unroll
                for (int fn = 0; fn < 4; fn++)
                    acc[fm][fn] = __builtin_amdgcn_mfma_f32_16x16x32_bf16(
                        Bf[kk][fn], af[fm], acc[fm][fn], 0, 0, 0);
        }

        const int row0 = tt * 128;
#pragma unroll
        for (int fm = 0; fm < 4; fm++) {
            const int row = row0 + wm * 64 + fm * 16 + lr;
            if (row < M) {
#pragma unroll
                for (int fn = 0; fn < 4; fn++) {
                    const int col0 = wn * 64 + fn * 16 + lk * 4;
                    const size_t off = (size_t)row * 128 + col0;
                    f32x4 vv = acc[fm][fn] + bs[fn];
                    if (RES == 1) {
                        f32x4 rr = *reinterpret_cast<const f32x4*>((const float*)res + off);
                        vv += rr;
                    }
                    if (RES == 2) {
                        uint2 rb = *reinterpret_cast<const uint2*>((const unsigned short*)res + off);
                        vv[0] += bf2f((unsigned short)(rb.x & 0xffff));
                        vv[1] += bf2f((unsigned short)(rb.x >> 16));
                        vv[2] += bf2f((unsigned short)(rb.y & 0xffff));
                        vv[3] += bf2f((unsigned short)(rb.y >> 16));
                    }
                    if (RELU) {
                        vv[0] = fmaxf(vv[0], 0.f); vv[1] = fmaxf(vv[1], 0.f);
                        vv[2] = fmaxf(vv[2], 0.f); vv[3] = fmaxf(vv[3], 0.f);
                    }
                    if (OUT_BF16) {
                        uint2 o; o.x = pack2(vv[0], vv[1]); o.y = pack2(vv[2], vv[3]);
                        *reinterpret_cast<uint2*>((unsigned short*)out + off) = o;
                    } else {
                        *reinterpret_cast<f32x4*>((float*)out + off) = vv;
                    }
                    if (OUT2) {
                        uint2 o; o.x = pack2(vv[0], vv[1]); o.y = pack2(vv[2], vv[3]);
                        *reinterpret_cast<uint2*>(out2 + off) = o;
                    }
                }
            }
        }
        __syncthreads();
        cur ^= 1;
    }
}

// ---------------------------------------------------------------------------
// Fused K+V GEMM: waves 0-1 compute K, waves 2-3 V. 64-row tiles.
// ---------------------------------------------------------------------------
__global__ __launch_bounds__(256, 2) void gemm_kv(
    const unsigned short* __restrict__ A,
    const unsigned short* __restrict__ WkT, const unsigned short* __restrict__ WvT,
    const float* __restrict__ bk, const float* __restrict__ bvv,
    unsigned short* __restrict__ K, unsigned short* __restrict__ V,
    int M, int ntiles)
{
    __shared__ __align__(16) unsigned short As[2][64 * 128];  // 2 x 16KB

    const int t = threadIdx.x, wave = t >> 6, lane = t & 63;
    const int lr = lane & 15, lk = lane >> 4;
    const int wsel = wave >> 1, wn = wave & 1;

    const unsigned short* WT = wsel ? WvT : WkT;
    const float* bias = wsel ? bvv : bk;
    unsigned short* out = wsel ? V : K;

    bf16x8 Bf[4][4];
    f32x4 bs[4];
#pragma unroll
    for (int fn = 0; fn < 4; fn++) {
        const int col0 = wn * 64 + fn * 16 + lk * 4;
        bs[fn] = *reinterpret_cast<const f32x4*>(bias + col0);
        const int n = wn * 64 + fn * 16 + lr;
#pragma unroll
        for (int kk = 0; kk < 4; kk++)
            Bf[kk][fn] = *reinterpret_cast<const bf16x8*>(WT + n * 128 + kk * 32 + lk * 8);
    }

    auto stage = [&](int buf, int row0) {
#pragma unroll
        for (int i = 0; i < 4; i++) {
            const int flat = (wave * 4 + i) * 1024 + lane * 16;
            const int r = flat >> 8;       // 0..63
            const int c = (flat >> 4) & 15;
            int gr = row0 + r; if (gr >= M) gr = M - 1;
            const void* g = A + (size_t)gr * 128 + ((c ^ (r & 7)) << 3);
            void* l = (void*)((char*)&As[buf][0] + (size_t)(wave * 4 + i) * 1024);
            gload_lds16(g, l);
        }
    };

    int tt = blockIdx.x;
    if (tt >= ntiles) return;
    int cur = 0;
    stage(0, tt * 64);
    __syncthreads();

    for (; tt < ntiles; tt += gridDim.x) {
        const int nxt = tt + gridDim.x;
        if (nxt < ntiles) stage(cur ^ 1, nxt * 64);

        f32x4 acc[4][4];
#pragma unroll
        for (int a = 0; a < 4; a++)
#pragma unroll
            for (int b = 0; b < 4; b++) acc[a][b] = (f32x4){0.f, 0.f, 0.f, 0.f};

#pragma unroll
        for (int kk = 0; kk < 4; kk++) {
            bf16x8 af[4];
#pragma unroll
            for (int fm = 0; fm < 4; fm++) {
                const int r = fm * 16 + lr;
                const int c = (kk * 4 + lk) ^ (r & 7);
                af[fm] = *reinterpret_cast<const bf16x8*>(&As[cur][r * 128 + c * 8]);
            }
#pragma unroll
            for (int fm = 0; fm < 4; fm++)
#pragma unroll
                for (int fn = 0; fn < 4; fn++)
                    acc[fm][fn] = __builtin_amdgcn_mfma_f32_16x16x32_bf16(
                        Bf[kk][fn], af[fm], acc[fm][fn], 0, 0, 0);
        }

        const int row0 = tt * 64;
#pragma unroll
        for (int fm = 0; fm < 4; fm++) {
            const int row = row0 + fm * 16 + lr;
            if (row < M) {
#pragma unroll
                for (int fn = 0; fn < 4; fn++) {
                    const int col0 = wn * 64 + fn * 16 + lk * 4;
                    f32x4 vv = acc[fm][fn] + bs[fn];
                    uint2 o; o.x = pack2(vv[0], vv[1]); o.y = pack2(vv[2], vv[3]);
                    *reinterpret_cast<uint2*>(out + (size_t)row * 128 + col0) = o;
                }
            }
        }
        __syncthreads();
        cur ^= 1;
    }
}

// ---------------------------------------------------------------------------
// CSR build
// ---------------------------------------------------------------------------
__global__ void hist_kernel(const int* __restrict__ dst, int* __restrict__ deg, int E_) {
    int e = blockIdx.x * 256 + threadIdx.x;
    if (e < E_) atomicAdd(&deg[dst[e]], 1);
}

__global__ __launch_bounds__(1024) void scan_kernel(
    const int* __restrict__ deg, int* __restrict__ rowptr,
    int* __restrict__ cursor, int N_)
{
    __shared__ int part[1024];
    const int t = threadIdx.x;
    const int chunk = (N_ + 1023) >> 10;
    const int base = t * chunk;
    int s = 0;
    for (int i = 0; i < chunk; i++) {
        int idx = base + i;
        if (idx < N_) s += deg[idx];
    }
    part[t] = s;
    __syncthreads();
    for (int off = 1; off < 1024; off <<= 1) {
        int v = (t >= off) ? part[t - off] : 0;
        __syncthreads();
        part[t] += v;
        __syncthreads();
    }
    int run = (t == 0) ? 0 : part[t - 1];
    for (int i = 0; i < chunk; i++) {
        int idx = base + i;
        if (idx < N_) {
            rowptr[idx] = run;
            cursor[idx] = run;
            run += deg[idx];
        }
    }
    if (t == 1023) rowptr[N_] = part[1023];
}

__global__ void scatter_kernel(const int* __restrict__ dst, int* __restrict__ cursor,
                               int* __restrict__ eidx, int E_) {
    int e = blockIdx.x * 256 + threadIdx.x;
    if (e >= E_) return;
    int pos = atomicAdd(&cursor[dst[e]], 1);
    eidx[pos] = e;
}

// ---------------------------------------------------------------------------
// Fused per-node attention: scores + online softmax + PV + normalize.
// One wave per node; lane holds dims 2l, 2l+1; head = lane>>4.
// ---------------------------------------------------------------------------
__global__ __launch_bounds__(256) void attn_kernel(
    const float* __restrict__ q, const unsigned short* __restrict__ k,
    const unsigned short* __restrict__ v,
    const int* __restrict__ rowptr, const int* __restrict__ eidx,
    unsigned short* __restrict__ ctxb, int N_)
{
    const int n = blockIdx.x * 4 + (threadIdx.x >> 6);
    if (n >= N_) return;
    const int lane = threadIdx.x & 63;

    const int beg = rowptr[n], end = rowptr[n + 1];
    unsigned* outp = (unsigned*)(ctxb + (size_t)n * 128 + lane * 2);
    if (beg == end) { *outp = 0; return; }

    float2 qv = *reinterpret_cast<const float2*>(q + (size_t)n * 128 + lane * 2);

    float m = -3.0e38f, l = 0.f, a0 = 0.f, a1 = 0.f;
    long e = eidx[beg];
    unsigned kc = *(const unsigned*)(k + e * 128 + lane * 2);
    unsigned vc = *(const unsigned*)(v + e * 128 + lane * 2);

    for (int i = beg; i < end; i++) {
        unsigned kcur = kc, vcur = vc;
        if (i + 1 < end) {
            long e2 = eidx[i + 1];
            kc = *(const unsigned*)(k + e2 * 128 + lane * 2);
            vc = *(const unsigned*)(v + e2 * 128 + lane * 2);
        }
        float s = bf2f((unsigned short)(kcur & 0xffff)) * qv.x
                + bf2f((unsigned short)(kcur >> 16)) * qv.y;
        s += __shfl_xor(s, 1, 64);
        s += __shfl_xor(s, 2, 64);
        s += __shfl_xor(s, 4, 64);
        s += __shfl_xor(s, 8, 64);
        s *= 0.17677669529663687f;   // 1/sqrt(32)
        float mn = fmaxf(m, s);
        float sc = __expf(m - mn);   // first iter: exp(-huge) = 0
        float p = __expf(s - mn);
        l = l * sc + p;
        a0 = a0 * sc + p * bf2f((unsigned short)(vcur & 0xffff));
        a1 = a1 * sc + p * bf2f((unsigned short)(vcur >> 16));
        m = mn;
    }
    float rl = 1.f / l;
    *outp = pack2(a0 * rl, a1 * rl);
}

// mail[n] = sum over incoming edges of h[e]  (bf16 out)
__global__ __launch_bounds__(256) void mail_csr(
    const unsigned short* __restrict__ h,
    const int* __restrict__ rowptr, const int* __restrict__ eidx,
    unsigned short* __restrict__ mailb, int N_)
{
    const int n = blockIdx.x * 4 + (threadIdx.x >> 6);
    if (n >= N_) return;
    const int lane = threadIdx.x & 63;

    const int beg = rowptr[n], end = rowptr[n + 1];
    float a0 = 0.f, a1 = 0.f;
    if (beg < end) {
        long e = eidx[beg];
        unsigned hc = *(const unsigned*)(h + e * 128 + lane * 2);
        for (int i = beg; i < end; i++) {
            unsigned hcur = hc;
            if (i + 1 < end) {
                long e2 = eidx[i + 1];
                hc = *(const unsigned*)(h + e2 * 128 + lane * 2);
            }
            a0 += bf2f((unsigned short)(hcur & 0xffff));
            a1 += bf2f((unsigned short)(hcur >> 16));
        }
    }
    *(unsigned*)(mailb + (size_t)n * 128 + lane * 2) = pack2(a0, a1);
}

// ---------------------------------------------------------------------------
struct W9 { const float* p[9]; };

__global__ void cvt_wT(W9 w, unsigned short* __restrict__ out) {
    const float* src = w.p[blockIdx.x];
    unsigned short* dst = out + (size_t)blockIdx.x * 16384;
    for (int idx = threadIdx.x; idx < 16384; idx += 256) {
        const int k = idx >> 7, n = idx & 127;
        dst[n * 128 + k] = f2bf(src[idx]);
    }
}

__global__ void cvt_bf16(const float* __restrict__ in, unsigned short* __restrict__ out, long n4) {
    long i = (long)blockIdx.x * 256 + threadIdx.x;
    if (i >= n4) return;
    float4 v = reinterpret_cast<const float4*>(in)[i];
    ushort4 o;
    o.x = f2bf(v.x); o.y = f2bf(v.y); o.z = f2bf(v.z); o.w = f2bf(v.w);
    reinterpret_cast<ushort4*>(out)[i] = o;
}

__device__ __forceinline__ unsigned pksub(unsigned a, unsigned b) {
    float r0 = bf2f((unsigned short)(a & 0xffff)) - bf2f((unsigned short)(b & 0xffff));
    float r1 = bf2f((unsigned short)(a >> 16))    - bf2f((unsigned short)(b >> 16));
    return pack2(r0, r1);
}

// m[e] = f_hb[src[e]] - h[e^1], all bf16, 8 elems (16B) per thread
__global__ void make_m(const unsigned short* __restrict__ f_hb, const unsigned short* __restrict__ h,
                       const int* __restrict__ src, unsigned short* __restrict__ m, long nchunks) {
    long i = (long)blockIdx.x * 256 + threadIdx.x;
    if (i >= nchunks) return;
    const long e = i >> 4;
    const int c = (int)(i & 15);
    uint4 hv = reinterpret_cast<const uint4*>(h)[i ^ 16];  // reverse edge: e^1
    uint4 fv = reinterpret_cast<const uint4*>(f_hb)[(long)src[e] * 16 + c];
    uint4 o;
    o.x = pksub(fv.x, hv.x); o.y = pksub(fv.y, hv.y);
    o.z = pksub(fv.z, hv.z); o.w = pksub(fv.w, hv.w);
    reinterpret_cast<uint4*>(m)[i] = o;
}

// ---------------------------------------------------------------------------
extern "C" void kernel_launch(void* const* d_in, const int* in_sizes, int n_in,
                              void* d_out, int out_size, void* d_ws, size_t ws_size,
                              hipStream_t stream)
{
    const float* f      = (const float*)d_in[0];
    const float* x      = (const float*)d_in[1];
    const int*   src    = (const int*)d_in[2];
    const int*   dst    = (const int*)d_in[3];
    const float* Wq     = (const float*)d_in[4];
    const float* bq     = (const float*)d_in[5];
    const float* Wk     = (const float*)d_in[6];
    const float* bk     = (const float*)d_in[7];
    const float* Wv     = (const float*)d_in[8];
    const float* bv     = (const float*)d_in[9];
    const float* Wo     = (const float*)d_in[10];
    const float* bo     = (const float*)d_in[11];
    const float* W_mp   = (const float*)d_in[12];
    const float* b_mp   = (const float*)d_in[13];
    const float* W_last = (const float*)d_in[14];
    const float* b_last = (const float*)d_in[15];

    const int N = in_sizes[0] / 128;
    const int E = in_sizes[1] / 128;

    char* p = (char*)d_ws;
    auto take = [&](size_t bytes) { char* r = p; p += (bytes + 255) & ~(size_t)255; return r; };
    unsigned short* w9T   = (unsigned short*)take(9 * 16384 * 2);
    unsigned short* xb    = (unsigned short*)take((size_t)E * 128 * 2);
    unsigned short* h1    = (unsigned short*)take((size_t)E * 128 * 2);
    unsigned short* kb    = (unsigned short*)take((size_t)E * 128 * 2);  // k, reused as m
    unsigned short* vb    = (unsigned short*)take((size_t)E * 128 * 2);
    unsigned short* fb    = (unsigned short*)take((size_t)N * 128 * 2);
    unsigned short* f_hb  = (unsigned short*)take((size_t)N * 128 * 2);
    unsigned short* ctxb  = (unsigned short*)take((size_t)N * 128 * 2);
    unsigned short* mailb = (unsigned short*)take((size_t)N * 128 * 2);
    float* f_h    = (float*)take((size_t)N * 128 * 4);
    float* q      = (float*)take((size_t)N * 128 * 4);
    int* deg      = (int*)take((size_t)N * 4);
    int* rowptr   = (int*)take((size_t)(N + 1) * 4);
    int* cursor   = (int*)take((size_t)N * 4);
    int* eidx     = (int*)take((size_t)E * 4);

    const unsigned short* WqT  = w9T + 0 * 16384;
    const unsigned short* WkT  = w9T + 1 * 16384;
    const unsigned short* WvT  = w9T + 2 * 16384;
    const unsigned short* WoT  = w9T + 3 * 16384;
    const unsigned short* Wm0T = w9T + 4 * 16384;
    const unsigned short* Wm1T = w9T + 5 * 16384;
    const unsigned short* WL0T = w9T + 6 * 16384;
    const unsigned short* WL1T = w9T + 7 * 16384;
    const unsigned short* WL2T = w9T + 8 * 16384;

    W9 w9;
    w9.p[0] = Wq; w9.p[1] = Wk; w9.p[2] = Wv; w9.p[3] = Wo;
    w9.p[4] = W_mp; w9.p[5] = W_mp + 16384;
    w9.p[6] = W_last; w9.p[7] = W_last + 16384; w9.p[8] = W_last + 32768;

    // --- setup: weights, bf16 copies, CSR ---
    cvt_wT<<<9, 256, 0, stream>>>(w9, w9T);
    cvt_bf16<<<(int)(((long)E * 32 + 255) / 256), 256, 0, stream>>>(x, xb, (long)E * 32);
    cvt_bf16<<<(int)(((long)N * 32 + 255) / 256), 256, 0, stream>>>(f, fb, (long)N * 32);
    hipMemcpyAsync(f_h, f, (size_t)N * 128 * 4, hipMemcpyDeviceToDevice, stream);

    hipMemsetAsync(deg, 0, (size_t)N * 4, stream);
    hist_kernel<<<(E + 255) / 256, 256, 0, stream>>>(dst, deg, E);
    scan_kernel<<<1, 1024, 0, stream>>>(deg, rowptr, cursor, N);
    scatter_kernel<<<(E + 255) / 256, 256, 0, stream>>>(dst, cursor, eidx, E);

    const int ntN = (N + 127) / 128;
    const int ntE128 = (E + 127) / 128;
    const int ntE64 = (E + 63) / 64;
    const int gNode = (N + 3) / 4;
    const long mchunks = (long)E * 16;

    const unsigned short* hc = xb;   // h starts as x
    for (int it = 0; it < 2; it++) {
        const unsigned short* fh_in = (it == 0) ? fb : f_hb;
        // q = f_h @ Wq + bq  (fp32 out)
        gemm_s<false, 0, false, false><<<ntN, 256, 0, stream>>>(
            fh_in, WqT, bq, nullptr, q, nullptr, N, ntN);
        // k, v fused
        gemm_kv<<<625, 256, 0, stream>>>(hc, WkT, WvT, bk, bv, kb, vb, E, ntE64);
        // fused segment attention -> ctxb (bf16)
        attn_kernel<<<gNode, 256, 0, stream>>>(q, kb, vb, rowptr, eidx, ctxb, N);
        // f_h = ctxb @ Wo + bo + f_h  (fp32), f_hb = bf16(f_h)
        gemm_s<false, 1, false, true><<<ntN, 256, 0, stream>>>(
            ctxb, WoT, bo, f_h, f_h, f_hb, N, ntN);
        // m = f_hb[src] - rev(h)  -> kb
        make_m<<<(int)((mchunks + 255) / 256), 256, 0, stream>>>(f_hb, hc, src, kb, mchunks);
        // h' = relu(x + m @ W_mp[it] + b_mp[it]) -> h1
        gemm_s<true, 2, true, false><<<625, 256, 0, stream>>>(
            kb, (it == 0) ? Wm0T : Wm1T, b_mp + (size_t)it * 128, xb, h1, nullptr, E, ntE128);
        hc = h1;
    }

    // mail = segment_sum(h, dst) -> mailb (bf16)
    mail_csr<<<gNode, 256, 0, stream>>>(hc, rowptr, eidx, mailb, N);

    // out = mail@WL0 + f_h@WL1 + f@WL2 + b_last
    gemm_s<false, 0, false, false><<<ntN, 256, 0, stream>>>(
        mailb, WL0T, b_last, nullptr, (float*)d_out, nullptr, N, ntN);
    gemm_s<false, 1, false, false><<<ntN, 256, 0, stream>>>(
        f_hb, WL1T, nullptr, d_out, (float*)d_out, nullptr, N, ntN);
    gemm_s<false, 1, false, false><<<ntN, 256, 0, stream>>>(
        fb, WL2T, nullptr, d_out, (float*)d_out, nullptr, N, ntN);
}

// Round 4
// 715.898 us; speedup vs baseline: 3.3597x; 1.2846x over previous
//
#include <hip/hip_runtime.h>
#include <hip/hip_bf16.h>

typedef __attribute__((ext_vector_type(8))) short bf16x8;
typedef __attribute__((ext_vector_type(4))) float f32x4;

__device__ __forceinline__ unsigned short f2bf(float f) {
    unsigned u = __float_as_uint(f);
    unsigned r = (u + 0x7FFFu + ((u >> 16) & 1u)) >> 16;  // RNE
    return (unsigned short)r;
}
__device__ __forceinline__ float bf2f(unsigned short b) {
    return __uint_as_float(((unsigned)b) << 16);
}
__device__ __forceinline__ unsigned pack2(float a, float b) {
    return (unsigned)f2bf(a) | ((unsigned)f2bf(b) << 16);
}
__device__ __forceinline__ unsigned pksub(unsigned a, unsigned b) {
    float r0 = bf2f((unsigned short)(a & 0xffff)) - bf2f((unsigned short)(b & 0xffff));
    float r1 = bf2f((unsigned short)(a >> 16))    - bf2f((unsigned short)(b >> 16));
    return pack2(r0, r1);
}

// async global->LDS, 16B/lane; LDS dest = wave-uniform base + lane*16 (m104);
// global src is per-lane (pre-swizzled source pattern, rule #21)
__device__ __forceinline__ void gload_lds16(const void* g, void* l) {
    __builtin_amdgcn_global_load_lds(
        (const __attribute__((address_space(1))) unsigned int*)g,
        (__attribute__((address_space(3))) unsigned int*)l,
        16, 0, 0);
}

// ---------------------------------------------------------------------------
// gemm_s: out[M x 128] = A[M x 128](bf16) @ W + bias (+res). 64-row tiles,
// 256 thr (4 waves, wave w -> cols w*32..w*32+31). WT bf16 [n][k]; B in VGPRs.
// mfma(Bf, af): lane holds 4 consecutive cols at fixed row -> vector stores.
// RES: 0 none, 1 fp32. OUT2: extra bf16 copy.
// ---------------------------------------------------------------------------
template<int RES, bool OUT_BF16, bool OUT2>
__global__ __launch_bounds__(256, 4) void gemm_s(
    const unsigned short* __restrict__ A, const unsigned short* __restrict__ WT,
    const float* __restrict__ bias, const void* res,
    void* out, unsigned short* __restrict__ out2, int M, int ntiles)
{
    __shared__ __align__(16) unsigned short As[2][64 * 128];  // 2 x 16KB

    const int t = threadIdx.x, wave = t >> 6, lane = t & 63;
    const int lr = lane & 15, lk = lane >> 4;

    bf16x8 Bf[4][2];
    f32x4 bs[2];
#pragma unroll
    for (int fn = 0; fn < 2; fn++) {
        const int col0 = wave * 32 + fn * 16 + lk * 4;
        bs[fn] = bias ? *reinterpret_cast<const f32x4*>(bias + col0)
                      : (f32x4){0.f, 0.f, 0.f, 0.f};
        const int n = wave * 32 + fn * 16 + lr;
#pragma unroll
        for (int kk = 0; kk < 4; kk++)
            Bf[kk][fn] = *reinterpret_cast<const bf16x8*>(WT + n * 128 + kk * 32 + lk * 8);
    }

    auto stage = [&](int buf, int row0) {
#pragma unroll
        for (int i = 0; i < 4; i++) {
            const int flat = (wave * 4 + i) * 1024 + lane * 16;
            const int r = flat >> 8, c = (flat >> 4) & 15;
            int gr = row0 + r; if (gr >= M) gr = M - 1;
            const void* g = A + (size_t)gr * 128 + ((c ^ (r & 7)) << 3);
            void* l = (void*)((char*)&As[buf][0] + (size_t)(wave * 4 + i) * 1024);
            gload_lds16(g, l);
        }
    };

    int tt = blockIdx.x;
    if (tt >= ntiles) return;
    int cur = 0;
    stage(0, tt * 64);
    __syncthreads();

    for (; tt < ntiles; tt += gridDim.x) {
        const int nxt = tt + gridDim.x;
        if (nxt < ntiles) stage(cur ^ 1, nxt * 64);

        f32x4 acc[4][2];
#pragma unroll
        for (int a = 0; a < 4; a++)
#pragma unroll
            for (int b = 0; b < 2; b++) acc[a][b] = (f32x4){0.f, 0.f, 0.f, 0.f};

#pragma unroll
        for (int kk = 0; kk < 4; kk++) {
            bf16x8 af[4];
#pragma unroll
            for (int fm = 0; fm < 4; fm++) {
                const int r = fm * 16 + lr;
                const int c = (kk * 4 + lk) ^ (r & 7);
                af[fm] = *reinterpret_cast<const bf16x8*>(&As[cur][r * 128 + c * 8]);
            }
#pragma unroll
            for (int fm = 0; fm < 4; fm++)
#pragma unroll
                for (int fn = 0; fn < 2; fn++)
                    acc[fm][fn] = __builtin_amdgcn_mfma_f32_16x16x32_bf16(
                        Bf[kk][fn], af[fm], acc[fm][fn], 0, 0, 0);
        }

        const int row0 = tt * 64;
#pragma unroll
        for (int fm = 0; fm < 4; fm++) {
            const int row = row0 + fm * 16 + lr;
            if (row < M) {
#pragma unroll
                for (int fn = 0; fn < 2; fn++) {
                    const int col0 = wave * 32 + fn * 16 + lk * 4;
                    const size_t off = (size_t)row * 128 + col0;
                    f32x4 vv = acc[fm][fn] + bs[fn];
                    if (RES == 1)
                        vv += *reinterpret_cast<const f32x4*>((const float*)res + off);
                    if (OUT_BF16) {
                        uint2 o; o.x = pack2(vv[0], vv[1]); o.y = pack2(vv[2], vv[3]);
                        *reinterpret_cast<uint2*>((unsigned short*)out + off) = o;
                    } else {
                        *reinterpret_cast<f32x4*>((float*)out + off) = vv;
                    }
                    if (OUT2) {
                        uint2 o; o.x = pack2(vv[0], vv[1]); o.y = pack2(vv[2], vv[3]);
                        *reinterpret_cast<uint2*>(out2 + off) = o;
                    }
                }
            }
        }
        __syncthreads();
        cur ^= 1;
    }
}

// ---------------------------------------------------------------------------
// gemm_kv_p: K/V GEMM with rows gathered by eidx -> outputs in CSR order.
// 512 thr: wave>>2 picks K/V, wave&3 picks 32-col strip. 64-row tiles.
// ---------------------------------------------------------------------------
__global__ __launch_bounds__(512, 4) void gemm_kv_p(
    const unsigned short* __restrict__ A, const int* __restrict__ eidx,
    const unsigned short* __restrict__ WkT, const unsigned short* __restrict__ WvT,
    const float* __restrict__ bk, const float* __restrict__ bvv,
    unsigned short* __restrict__ Kp, unsigned short* __restrict__ Vp,
    int E, int ntiles)
{
    __shared__ __align__(16) unsigned short As[2][64 * 128];

    const int t = threadIdx.x, wave = t >> 6, lane = t & 63;
    const int lr = lane & 15, lk = lane >> 4;
    const int wsel = wave >> 2, wn = wave & 3;

    const unsigned short* WT = wsel ? WvT : WkT;
    const float* bias = wsel ? bvv : bk;
    unsigned short* out = wsel ? Vp : Kp;

    bf16x8 Bf[4][2];
    f32x4 bs[2];
#pragma unroll
    for (int fn = 0; fn < 2; fn++) {
        const int col0 = wn * 32 + fn * 16 + lk * 4;
        bs[fn] = *reinterpret_cast<const f32x4*>(bias + col0);
        const int n = wn * 32 + fn * 16 + lr;
#pragma unroll
        for (int kk = 0; kk < 4; kk++)
            Bf[kk][fn] = *reinterpret_cast<const bf16x8*>(WT + n * 128 + kk * 32 + lk * 8);
    }

    auto stage = [&](int buf, int row0) {
#pragma unroll
        for (int i = 0; i < 2; i++) {
            const int flat = (wave * 2 + i) * 1024 + lane * 16;
            const int r = flat >> 8, c = (flat >> 4) & 15;
            int pr = row0 + r; if (pr >= E) pr = E - 1;
            const int er = eidx[pr];
            const void* g = A + (size_t)er * 128 + ((c ^ (r & 7)) << 3);
            void* l = (void*)((char*)&As[buf][0] + (size_t)(wave * 2 + i) * 1024);
            gload_lds16(g, l);
        }
    };

    int tt = blockIdx.x;
    if (tt >= ntiles) return;
    int cur = 0;
    stage(0, tt * 64);
    __syncthreads();

    for (; tt < ntiles; tt += gridDim.x) {
        const int nxt = tt + gridDim.x;
        if (nxt < ntiles) stage(cur ^ 1, nxt * 64);

        f32x4 acc[4][2];
#pragma unroll
        for (int a = 0; a < 4; a++)
#pragma unroll
            for (int b = 0; b < 2; b++) acc[a][b] = (f32x4){0.f, 0.f, 0.f, 0.f};

#pragma unroll
        for (int kk = 0; kk < 4; kk++) {
            bf16x8 af[4];
#pragma unroll
            for (int fm = 0; fm < 4; fm++) {
                const int r = fm * 16 + lr;
                const int c = (kk * 4 + lk) ^ (r & 7);
                af[fm] = *reinterpret_cast<const bf16x8*>(&As[cur][r * 128 + c * 8]);
            }
#pragma unroll
            for (int fm = 0; fm < 4; fm++)
#pragma unroll
                for (int fn = 0; fn < 2; fn++)
                    acc[fm][fn] = __builtin_amdgcn_mfma_f32_16x16x32_bf16(
                        Bf[kk][fn], af[fm], acc[fm][fn], 0, 0, 0);
        }

        const int row0 = tt * 64;
#pragma unroll
        for (int fm = 0; fm < 4; fm++) {
            const int row = row0 + fm * 16 + lr;
            if (row < E) {
#pragma unroll
                for (int fn = 0; fn < 2; fn++) {
                    const int col0 = wn * 32 + fn * 16 + lk * 4;
                    f32x4 vv = acc[fm][fn] + bs[fn];
                    uint2 o; o.x = pack2(vv[0], vv[1]); o.y = pack2(vv[2], vv[3]);
                    *reinterpret_cast<uint2*>(out + (size_t)row * 128 + col0) = o;
                }
            }
        }
        __syncthreads();
        cur ^= 1;
    }
}

// ---------------------------------------------------------------------------
// gemm_mrelu: h' = relu(x + (f_hb[src[e]] - h[e^1]) @ Wm + b). Reg-staged
// (T14 issue-early/write-late): loads at loop top, LDS write after MFMA.
// ---------------------------------------------------------------------------
__global__ __launch_bounds__(256, 3) void gemm_mrelu(
    const unsigned short* __restrict__ f_hb, const unsigned short* __restrict__ h,
    const int* __restrict__ src, const unsigned short* __restrict__ WT,
    const float* __restrict__ bias, const unsigned short* __restrict__ resx,
    unsigned short* __restrict__ out, int E, int ntiles)
{
    __shared__ __align__(16) unsigned short As[2][64 * 128];

    const int t = threadIdx.x, wave = t >> 6, lane = t & 63;
    const int lr = lane & 15, lk = lane >> 4;

    bf16x8 Bf[4][2];
    f32x4 bs[2];
#pragma unroll
    for (int fn = 0; fn < 2; fn++) {
        const int col0 = wave * 32 + fn * 16 + lk * 4;
        bs[fn] = *reinterpret_cast<const f32x4*>(bias + col0);
        const int n = wave * 32 + fn * 16 + lr;
#pragma unroll
        for (int kk = 0; kk < 4; kk++)
            Bf[kk][fn] = *reinterpret_cast<const bf16x8*>(WT + n * 128 + kk * 32 + lk * 8);
    }

    uint4 Lh[4], Lf[4];
    auto load_t = [&](int row0) {
#pragma unroll
        for (int i = 0; i < 4; i++) {
            const int flat = (wave * 4 + i) * 1024 + lane * 16;
            const int r = flat >> 8, c = (flat >> 4) & 15;
            int e = row0 + r; if (e >= E) e = E - 1;
            Lh[i] = *reinterpret_cast<const uint4*>(h + (size_t)(e ^ 1) * 128 + c * 8);
            const int se = src[e];
            Lf[i] = *reinterpret_cast<const uint4*>(f_hb + (size_t)se * 128 + c * 8);
        }
    };
    auto write_t = [&](int buf) {
#pragma unroll
        for (int i = 0; i < 4; i++) {
            const int flat = (wave * 4 + i) * 1024 + lane * 16;
            const int r = flat >> 8, c = (flat >> 4) & 15;
            uint4 d;
            d.x = pksub(Lf[i].x, Lh[i].x); d.y = pksub(Lf[i].y, Lh[i].y);
            d.z = pksub(Lf[i].z, Lh[i].z); d.w = pksub(Lf[i].w, Lh[i].w);
            *reinterpret_cast<uint4*>(&As[buf][r * 128 + ((c ^ (r & 7)) << 3)]) = d;
        }
    };

    int tt = blockIdx.x;
    if (tt >= ntiles) return;
    load_t(tt * 64);
    write_t(0);
    int cur = 0;
    __syncthreads();

    for (; tt < ntiles; tt += gridDim.x) {
        const int nxt = tt + gridDim.x;
        if (nxt < ntiles) load_t(nxt * 64);   // issue early; consumed after MFMA

        f32x4 acc[4][2];
#pragma unroll
        for (int a = 0; a < 4; a++)
#pragma unroll
            for (int b = 0; b < 2; b++) acc[a][b] = (f32x4){0.f, 0.f, 0.f, 0.f};

#pragma unroll
        for (int kk = 0; kk < 4; kk++) {
            bf16x8 af[4];
#pragma unroll
            for (int fm = 0; fm < 4; fm++) {
                const int r = fm * 16 + lr;
                const int c = (kk * 4 + lk) ^ (r & 7);
                af[fm] = *reinterpret_cast<const bf16x8*>(&As[cur][r * 128 + c * 8]);
            }
#pragma unroll
            for (int fm = 0; fm < 4; fm++)
#pragma unroll
                for (int fn = 0; fn < 2; fn++)
                    acc[fm][fn] = __builtin_amdgcn_mfma_f32_16x16x32_bf16(
                        Bf[kk][fn], af[fm], acc[fm][fn], 0, 0, 0);
        }

        const int row0 = tt * 64;
#pragma unroll
        for (int fm = 0; fm < 4; fm++) {
            const int row = row0 + fm * 16 + lr;
            if (row < E) {
#pragma unroll
                for (int fn = 0; fn < 2; fn++) {
                    const int col0 = wave * 32 + fn * 16 + lk * 4;
                    const size_t off = (size_t)row * 128 + col0;
                    f32x4 vv = acc[fm][fn] + bs[fn];
                    uint2 rb = *reinterpret_cast<const uint2*>(resx + off);
                    vv[0] += bf2f((unsigned short)(rb.x & 0xffff));
                    vv[1] += bf2f((unsigned short)(rb.x >> 16));
                    vv[2] += bf2f((unsigned short)(rb.y & 0xffff));
                    vv[3] += bf2f((unsigned short)(rb.y >> 16));
                    vv[0] = fmaxf(vv[0], 0.f); vv[1] = fmaxf(vv[1], 0.f);
                    vv[2] = fmaxf(vv[2], 0.f); vv[3] = fmaxf(vv[3], 0.f);
                    uint2 o; o.x = pack2(vv[0], vv[1]); o.y = pack2(vv[2], vv[3]);
                    *reinterpret_cast<uint2*>(out + off) = o;
                }
            }
        }

        if (nxt < ntiles) write_t(cur ^ 1);   // write-late: loads have landed
        __syncthreads();
        cur ^= 1;
    }
}

// ---------------------------------------------------------------------------
// CSR build
// ---------------------------------------------------------------------------
__global__ void hist_kernel(const int* __restrict__ dst, int* __restrict__ deg, int E_) {
    int e = blockIdx.x * 256 + threadIdx.x;
    if (e < E_) atomicAdd(&deg[dst[e]], 1);
}

__global__ __launch_bounds__(1024) void scan_kernel(
    const int* __restrict__ deg, int* __restrict__ rowptr,
    int* __restrict__ cursor, int N_)
{
    __shared__ int part[1024];
    const int t = threadIdx.x;
    const int chunk = (N_ + 1023) >> 10;
    const int base = t * chunk;
    int s = 0;
    for (int i = 0; i < chunk; i++) {
        int idx = base + i;
        if (idx < N_) s += deg[idx];
    }
    part[t] = s;
    __syncthreads();
    for (int off = 1; off < 1024; off <<= 1) {
        int v = (t >= off) ? part[t - off] : 0;
        __syncthreads();
        part[t] += v;
        __syncthreads();
    }
    int run = (t == 0) ? 0 : part[t - 1];
    for (int i = 0; i < chunk; i++) {
        int idx = base + i;
        if (idx < N_) {
            rowptr[idx] = run;
            cursor[idx] = run;
            run += deg[idx];
        }
    }
    if (t == 1023) rowptr[N_] = part[1023];
}

__global__ void scatter_kernel(const int* __restrict__ dst, int* __restrict__ cursor,
                               int* __restrict__ eidx, int E_) {
    int e = blockIdx.x * 256 + threadIdx.x;
    if (e >= E_) return;
    int pos = atomicAdd(&cursor[dst[e]], 1);
    eidx[pos] = e;
}

// ---------------------------------------------------------------------------
// Fused per-node attention over CSR-ordered K/V (contiguous rows per node).
// One wave per node; lane holds dims 2l,2l+1.
// ---------------------------------------------------------------------------
__global__ __launch_bounds__(256) void attn_kernel(
    const float* __restrict__ q, const unsigned short* __restrict__ kp,
    const unsigned short* __restrict__ vp,
    const int* __restrict__ rowptr, unsigned short* __restrict__ ctxb, int N_)
{
    const int n = blockIdx.x * 4 + (threadIdx.x >> 6);
    if (n >= N_) return;
    const int lane = threadIdx.x & 63;

    const int beg = rowptr[n], end = rowptr[n + 1];
    unsigned* outp = (unsigned*)(ctxb + (size_t)n * 128 + lane * 2);
    if (beg == end) { *outp = 0; return; }

    float2 qv = *reinterpret_cast<const float2*>(q + (size_t)n * 128 + lane * 2);

    float m = -3.0e38f, l = 0.f, a0 = 0.f, a1 = 0.f;
    unsigned kc = *(const unsigned*)(kp + (size_t)beg * 128 + lane * 2);
    unsigned vc = *(const unsigned*)(vp + (size_t)beg * 128 + lane * 2);

    for (int i = beg; i < end; i++) {
        unsigned kcur = kc, vcur = vc;
        if (i + 1 < end) {
            kc = *(const unsigned*)(kp + (size_t)(i + 1) * 128 + lane * 2);
            vc = *(const unsigned*)(vp + (size_t)(i + 1) * 128 + lane * 2);
        }
        float s = bf2f((unsigned short)(kcur & 0xffff)) * qv.x
                + bf2f((unsigned short)(kcur >> 16)) * qv.y;
        s += __shfl_xor(s, 1, 64);
        s += __shfl_xor(s, 2, 64);
        s += __shfl_xor(s, 4, 64);
        s += __shfl_xor(s, 8, 64);
        s *= 0.17677669529663687f;   // 1/sqrt(32)
        float mn = fmaxf(m, s);
        float sc = __expf(m - mn);
        float p = __expf(s - mn);
        l = l * sc + p;
        a0 = a0 * sc + p * bf2f((unsigned short)(vcur & 0xffff));
        a1 = a1 * sc + p * bf2f((unsigned short)(vcur >> 16));
        m = mn;
    }
    float rl = 1.f / l;
    *outp = pack2(a0 * rl, a1 * rl);
}

// mail[n] = sum over incoming edges of h[e]  (gathered via eidx)
__global__ __launch_bounds__(256) void mail_csr(
    const unsigned short* __restrict__ h,
    const int* __restrict__ rowptr, const int* __restrict__ eidx,
    unsigned short* __restrict__ mailb, int N_)
{
    const int n = blockIdx.x * 4 + (threadIdx.x >> 6);
    if (n >= N_) return;
    const int lane = threadIdx.x & 63;

    const int beg = rowptr[n], end = rowptr[n + 1];
    float a0 = 0.f, a1 = 0.f;
    if (beg < end) {
        long e = eidx[beg];
        unsigned hc = *(const unsigned*)(h + e * 128 + lane * 2);
        for (int i = beg; i < end; i++) {
            unsigned hcur = hc;
            if (i + 1 < end) {
                long e2 = eidx[i + 1];
                hc = *(const unsigned*)(h + e2 * 128 + lane * 2);
            }
            a0 += bf2f((unsigned short)(hcur & 0xffff));
            a1 += bf2f((unsigned short)(hcur >> 16));
        }
    }
    *(unsigned*)(mailb + (size_t)n * 128 + lane * 2) = pack2(a0, a1);
}

// ---------------------------------------------------------------------------
struct W9 { const float* p[9]; };

__global__ void cvt_wT(W9 w, unsigned short* __restrict__ out) {
    const float* src = w.p[blockIdx.x];
    unsigned short* dst = out + (size_t)blockIdx.x * 16384;
    for (int idx = threadIdx.x; idx < 16384; idx += 256) {
        const int k = idx >> 7, n = idx & 127;
        dst[n * 128 + k] = f2bf(src[idx]);
    }
}

__global__ void cvt_bf16(const float* __restrict__ in, unsigned short* __restrict__ out, long n4) {
    long i = (long)blockIdx.x * 256 + threadIdx.x;
    if (i >= n4) return;
    float4 v = reinterpret_cast<const float4*>(in)[i];
    ushort4 o;
    o.x = f2bf(v.x); o.y = f2bf(v.y); o.z = f2bf(v.z); o.w = f2bf(v.w);
    reinterpret_cast<ushort4*>(out)[i] = o;
}

// fb = bf16(f), f_h = f  (one pass)
__global__ void prep_f(const float* __restrict__ f, unsigned short* __restrict__ fb,
                       float* __restrict__ f_h, int n4) {
    int i = blockIdx.x * 256 + threadIdx.x;
    if (i >= n4) return;
    float4 v = reinterpret_cast<const float4*>(f)[i];
    reinterpret_cast<float4*>(f_h)[i] = v;
    ushort4 o;
    o.x = f2bf(v.x); o.y = f2bf(v.y); o.z = f2bf(v.z); o.w = f2bf(v.w);
    reinterpret_cast<ushort4*>(fb)[i] = o;
}

// ---------------------------------------------------------------------------
extern "C" void kernel_launch(void* const* d_in, const int* in_sizes, int n_in,
                              void* d_out, int out_size, void* d_ws, size_t ws_size,
                              hipStream_t stream)
{
    const float* f      = (const float*)d_in[0];
    const float* x      = (const float*)d_in[1];
    const int*   src    = (const int*)d_in[2];
    const int*   dst    = (const int*)d_in[3];
    const float* Wq     = (const float*)d_in[4];
    const float* bq     = (const float*)d_in[5];
    const float* Wk     = (const float*)d_in[6];
    const float* bk     = (const float*)d_in[7];
    const float* Wv     = (const float*)d_in[8];
    const float* bv     = (const float*)d_in[9];
    const float* Wo     = (const float*)d_in[10];
    const float* bo     = (const float*)d_in[11];
    const float* W_mp   = (const float*)d_in[12];
    const float* b_mp   = (const float*)d_in[13];
    const float* W_last = (const float*)d_in[14];
    const float* b_last = (const float*)d_in[15];

    const int N = in_sizes[0] / 128;
    const int E = in_sizes[1] / 128;

    char* p = (char*)d_ws;
    auto take = [&](size_t bytes) { char* r = p; p += (bytes + 255) & ~(size_t)255; return r; };
    unsigned short* w9T   = (unsigned short*)take(9 * 16384 * 2);
    unsigned short* xb    = (unsigned short*)take((size_t)E * 128 * 2);
    unsigned short* h1    = (unsigned short*)take((size_t)E * 128 * 2);
    unsigned short* h2    = (unsigned short*)take((size_t)E * 128 * 2);
    unsigned short* kp    = (unsigned short*)take((size_t)E * 128 * 2);
    unsigned short* vp    = (unsigned short*)take((size_t)E * 128 * 2);
    unsigned short* fb    = (unsigned short*)take((size_t)N * 128 * 2);
    unsigned short* f_hb  = (unsigned short*)take((size_t)N * 128 * 2);
    unsigned short* ctxb  = (unsigned short*)take((size_t)N * 128 * 2);
    unsigned short* mailb = (unsigned short*)take((size_t)N * 128 * 2);
    float* f_h    = (float*)take((size_t)N * 128 * 4);
    float* q      = (float*)take((size_t)N * 128 * 4);
    int* deg      = (int*)take((size_t)N * 4);
    int* rowptr   = (int*)take((size_t)(N + 1) * 4);
    int* cursor   = (int*)take((size_t)N * 4);
    int* eidx     = (int*)take((size_t)E * 4);

    const unsigned short* WqT  = w9T + 0 * 16384;
    const unsigned short* WkT  = w9T + 1 * 16384;
    const unsigned short* WvT  = w9T + 2 * 16384;
    const unsigned short* WoT  = w9T + 3 * 16384;
    const unsigned short* Wm0T = w9T + 4 * 16384;
    const unsigned short* Wm1T = w9T + 5 * 16384;
    const unsigned short* WL0T = w9T + 6 * 16384;
    const unsigned short* WL1T = w9T + 7 * 16384;
    const unsigned short* WL2T = w9T + 8 * 16384;

    W9 w9;
    w9.p[0] = Wq; w9.p[1] = Wk; w9.p[2] = Wv; w9.p[3] = Wo;
    w9.p[4] = W_mp; w9.p[5] = W_mp + 16384;
    w9.p[6] = W_last; w9.p[7] = W_last + 16384; w9.p[8] = W_last + 32768;

    // --- setup ---
    cvt_wT<<<9, 256, 0, stream>>>(w9, w9T);
    cvt_bf16<<<(int)(((long)E * 32 + 255) / 256), 256, 0, stream>>>(x, xb, (long)E * 32);
    prep_f<<<(N * 32 + 255) / 256, 256, 0, stream>>>(f, fb, f_h, N * 32);

    hipMemsetAsync(deg, 0, (size_t)N * 4, stream);
    hist_kernel<<<(E + 255) / 256, 256, 0, stream>>>(dst, deg, E);
    scan_kernel<<<1, 1024, 0, stream>>>(deg, rowptr, cursor, N);
    scatter_kernel<<<(E + 255) / 256, 256, 0, stream>>>(dst, cursor, eidx, E);

    const int ntN = (N + 63) / 64;       // 313
    const int ntE = (E + 63) / 64;       // 6250
    const int gNode = (N + 3) / 4;

    const unsigned short* hc = xb;   // h starts as x
    unsigned short* houts[2] = { h1, h2 };
    for (int it = 0; it < 2; it++) {
        const unsigned short* fh_in = (it == 0) ? fb : f_hb;
        // q = f_h @ Wq + bq  (fp32)
        gemm_s<0, false, false><<<ntN, 256, 0, stream>>>(
            fh_in, WqT, bq, nullptr, q, nullptr, N, ntN);
        // K,V in CSR-permuted order
        gemm_kv_p<<<512, 512, 0, stream>>>(hc, eidx, WkT, WvT, bk, bv, kp, vp, E, ntE);
        // fused segment attention -> ctxb (bf16)
        attn_kernel<<<gNode, 256, 0, stream>>>(q, kp, vp, rowptr, ctxb, N);
        // f_h = ctxb @ Wo + bo + f_h (fp32) ; f_hb = bf16 copy
        gemm_s<1, false, true><<<ntN, 256, 0, stream>>>(
            ctxb, WoT, bo, f_h, f_h, f_hb, N, ntN);
        // h' = relu(x + (f_hb[src] - rev(h)) @ Wm + b)
        gemm_mrelu<<<768, 256, 0, stream>>>(
            f_hb, hc, src, (it == 0) ? Wm0T : Wm1T, b_mp + (size_t)it * 128,
            xb, houts[it], E, ntE);
        hc = houts[it];
    }

    // mail = segment_sum(h, dst) -> mailb
    mail_csr<<<gNode, 256, 0, stream>>>(hc, rowptr, eidx, mailb, N);

    // out = mail@WL0 + f_h@WL1 + f@WL2 + b_last
    gemm_s<0, false, false><<<ntN, 256, 0, stream>>>(
        mailb, WL0T, b_last, nullptr, (float*)d_out, nullptr, N, ntN);
    gemm_s<1, false, false><<<ntN, 256, 0, stream>>>(
        f_hb, WL1T, nullptr, d_out, (float*)d_out, nullptr, N, ntN);
    gemm_s<1, false, false><<<ntN, 256, 0, stream>>>(
        fb, WL2T, nullptr, d_out, (float*)d_out, nullptr, N, ntN);
}

// Round 5
// 708.379 us; speedup vs baseline: 3.3954x; 1.0106x over previous
//
#include <hip/hip_runtime.h>
#include <hip/hip_bf16.h>

typedef __attribute__((ext_vector_type(8))) short bf16x8;
typedef __attribute__((ext_vector_type(4))) float f32x4;

__device__ __forceinline__ unsigned short f2bf(float f) {
    unsigned u = __float_as_uint(f);
    unsigned r = (u + 0x7FFFu + ((u >> 16) & 1u)) >> 16;  // RNE
    return (unsigned short)r;
}
__device__ __forceinline__ float bf2f(unsigned short b) {
    return __uint_as_float(((unsigned)b) << 16);
}
__device__ __forceinline__ unsigned pack2(float a, float b) {
    return (unsigned)f2bf(a) | ((unsigned)f2bf(b) << 16);
}
__device__ __forceinline__ unsigned pksub(unsigned a, unsigned b) {
    float r0 = bf2f((unsigned short)(a & 0xffff)) - bf2f((unsigned short)(b & 0xffff));
    float r1 = bf2f((unsigned short)(a >> 16))    - bf2f((unsigned short)(b >> 16));
    return pack2(r0, r1);
}

__device__ __forceinline__ void gload_lds16(const void* g, void* l) {
    __builtin_amdgcn_global_load_lds(
        (const __attribute__((address_space(1))) unsigned int*)g,
        (__attribute__((address_space(3))) unsigned int*)l,
        16, 0, 0);
}

// ---------------------------------------------------------------------------
// gemm_s: out[M x 128] = A[M x 128](bf16) @ W + bias (+res). 64-row tiles,
// 256 thr (4 waves x 32 cols). WT bf16 [n][k]; B in VGPRs. Persistent.
// ---------------------------------------------------------------------------
template<int RES, bool OUT_BF16, bool OUT2>
__global__ __launch_bounds__(256, 4) void gemm_s(
    const unsigned short* __restrict__ A, const unsigned short* __restrict__ WT,
    const float* __restrict__ bias, const void* res,
    void* out, unsigned short* __restrict__ out2, int M, int ntiles)
{
    __shared__ __align__(16) unsigned short As[2][64 * 128];

    const int t = threadIdx.x, wave = t >> 6, lane = t & 63;
    const int lr = lane & 15, lk = lane >> 4;

    bf16x8 Bf[4][2];
    f32x4 bs[2];
#pragma unroll
    for (int fn = 0; fn < 2; fn++) {
        const int col0 = wave * 32 + fn * 16 + lk * 4;
        bs[fn] = bias ? *reinterpret_cast<const f32x4*>(bias + col0)
                      : (f32x4){0.f, 0.f, 0.f, 0.f};
        const int n = wave * 32 + fn * 16 + lr;
#pragma unroll
        for (int kk = 0; kk < 4; kk++)
            Bf[kk][fn] = *reinterpret_cast<const bf16x8*>(WT + n * 128 + kk * 32 + lk * 8);
    }

    auto stage = [&](int buf, int row0) {
#pragma unroll
        for (int i = 0; i < 4; i++) {
            const int flat = (wave * 4 + i) * 1024 + lane * 16;
            const int r = flat >> 8, c = (flat >> 4) & 15;
            int gr = row0 + r; if (gr >= M) gr = M - 1;
            const void* g = A + (size_t)gr * 128 + ((c ^ (r & 7)) << 3);
            void* l = (void*)((char*)&As[buf][0] + (size_t)(wave * 4 + i) * 1024);
            gload_lds16(g, l);
        }
    };

    int tt = blockIdx.x;
    if (tt >= ntiles) return;
    int cur = 0;
    stage(0, tt * 64);
    __syncthreads();

    for (; tt < ntiles; tt += gridDim.x) {
        const int nxt = tt + gridDim.x;
        if (nxt < ntiles) stage(cur ^ 1, nxt * 64);

        f32x4 acc[4][2];
#pragma unroll
        for (int a = 0; a < 4; a++)
#pragma unroll
            for (int b = 0; b < 2; b++) acc[a][b] = (f32x4){0.f, 0.f, 0.f, 0.f};

#pragma unroll
        for (int kk = 0; kk < 4; kk++) {
            bf16x8 af[4];
#pragma unroll
            for (int fm = 0; fm < 4; fm++) {
                const int r = fm * 16 + lr;
                const int c = (kk * 4 + lk) ^ (r & 7);
                af[fm] = *reinterpret_cast<const bf16x8*>(&As[cur][r * 128 + c * 8]);
            }
#pragma unroll
            for (int fm = 0; fm < 4; fm++)
#pragma unroll
                for (int fn = 0; fn < 2; fn++)
                    acc[fm][fn] = __builtin_amdgcn_mfma_f32_16x16x32_bf16(
                        Bf[kk][fn], af[fm], acc[fm][fn], 0, 0, 0);
        }

        const int row0 = tt * 64;
#pragma unroll
        for (int fm = 0; fm < 4; fm++) {
            const int row = row0 + fm * 16 + lr;
            if (row < M) {
#pragma unroll
                for (int fn = 0; fn < 2; fn++) {
                    const int col0 = wave * 32 + fn * 16 + lk * 4;
                    const size_t off = (size_t)row * 128 + col0;
                    f32x4 vv = acc[fm][fn] + bs[fn];
                    if (RES == 1)
                        vv += *reinterpret_cast<const f32x4*>((const float*)res + off);
                    if (OUT_BF16) {
                        uint2 o; o.x = pack2(vv[0], vv[1]); o.y = pack2(vv[2], vv[3]);
                        *reinterpret_cast<uint2*>((unsigned short*)out + off) = o;
                    } else {
                        *reinterpret_cast<f32x4*>((float*)out + off) = vv;
                    }
                    if (OUT2) {
                        uint2 o; o.x = pack2(vv[0], vv[1]); o.y = pack2(vv[2], vv[3]);
                        *reinterpret_cast<uint2*>(out2 + off) = o;
                    }
                }
            }
        }
        __syncthreads();
        cur ^= 1;
    }
}

// ---------------------------------------------------------------------------
// gemm_q512: qkt[M x 512](bf16) = A[M x 128](bf16) @ McatT + cbias.
// 512 thr (8 waves x 64 cols), one 64-row tile per block.
// ---------------------------------------------------------------------------
__global__ __launch_bounds__(512, 2) void gemm_q512(
    const unsigned short* __restrict__ A, const unsigned short* __restrict__ WT,
    const float* __restrict__ bias, unsigned short* __restrict__ out, int M)
{
    __shared__ __align__(16) unsigned short As[64 * 128];

    const int t = threadIdx.x, wave = t >> 6, lane = t & 63;
    const int lr = lane & 15, lk = lane >> 4;

    bf16x8 Bf[4][4];
    f32x4 bs[4];
#pragma unroll
    for (int fn = 0; fn < 4; fn++) {
        const int col0 = wave * 64 + fn * 16 + lk * 4;
        bs[fn] = *reinterpret_cast<const f32x4*>(bias + col0);
        const int n = wave * 64 + fn * 16 + lr;
#pragma unroll
        for (int kk = 0; kk < 4; kk++)
            Bf[kk][fn] = *reinterpret_cast<const bf16x8*>(WT + n * 128 + kk * 32 + lk * 8);
    }

    const int row0 = blockIdx.x * 64;
#pragma unroll
    for (int i = 0; i < 2; i++) {
        const int flat = (i * 512 + t) * 16;
        const int r = flat >> 8, c = (flat >> 4) & 15;
        int gr = row0 + r; if (gr >= M) gr = M - 1;
        const void* g = A + (size_t)gr * 128 + ((c ^ (r & 7)) << 3);
        void* l = (void*)((char*)&As[0] + (size_t)(i * 512 + wave * 64) * 16 + 0);
        gload_lds16(g, l);
    }
    __syncthreads();

    f32x4 acc[4][4];
#pragma unroll
    for (int a = 0; a < 4; a++)
#pragma unroll
        for (int b = 0; b < 4; b++) acc[a][b] = (f32x4){0.f, 0.f, 0.f, 0.f};

#pragma unroll
    for (int kk = 0; kk < 4; kk++) {
        bf16x8 af[4];
#pragma unroll
        for (int fm = 0; fm < 4; fm++) {
            const int r = fm * 16 + lr;
            const int c = (kk * 4 + lk) ^ (r & 7);
            af[fm] = *reinterpret_cast<const bf16x8*>(&As[r * 128 + c * 8]);
        }
#pragma unroll
        for (int fm = 0; fm < 4; fm++)
#pragma unroll
            for (int fn = 0; fn < 4; fn++)
                acc[fm][fn] = __builtin_amdgcn_mfma_f32_16x16x32_bf16(
                    Bf[kk][fn], af[fm], acc[fm][fn], 0, 0, 0);
    }

#pragma unroll
    for (int fm = 0; fm < 4; fm++) {
        const int row = row0 + fm * 16 + lr;
        if (row < M) {
#pragma unroll
            for (int fn = 0; fn < 4; fn++) {
                const int col0 = wave * 64 + fn * 16 + lk * 4;
                f32x4 vv = acc[fm][fn] + bs[fn];
                uint2 o; o.x = pack2(vv[0], vv[1]); o.y = pack2(vv[2], vv[3]);
                *reinterpret_cast<uint2*>(out + (size_t)row * 512 + col0) = o;
            }
        }
    }
}

// ---------------------------------------------------------------------------
// gemm_k512: f_h[M x 128](fp32) += A[M x 512](bf16) @ PcatT + bias2;
// also emits f_hb bf16. 256 thr (4 waves x 32 cols), one 64-row tile/block.
// ---------------------------------------------------------------------------
__global__ __launch_bounds__(256, 2) void gemm_k512(
    const unsigned short* __restrict__ A, const unsigned short* __restrict__ WT,
    const float* __restrict__ bias, float* __restrict__ f_h,
    unsigned short* __restrict__ f_hb, int M)
{
    __shared__ __align__(16) unsigned short As[64 * 512];  // 64KB

    const int t = threadIdx.x, wave = t >> 6, lane = t & 63;
    const int lr = lane & 15, lk = lane >> 4;

    bf16x8 Bf[16][2];
    f32x4 bs[2];
#pragma unroll
    for (int fn = 0; fn < 2; fn++) {
        const int col0 = wave * 32 + fn * 16 + lk * 4;
        bs[fn] = *reinterpret_cast<const f32x4*>(bias + col0);
        const int n = wave * 32 + fn * 16 + lr;
#pragma unroll
        for (int kk = 0; kk < 16; kk++)
            Bf[kk][fn] = *reinterpret_cast<const bf16x8*>(WT + n * 512 + kk * 32 + lk * 8);
    }

    const int row0 = blockIdx.x * 64;
#pragma unroll
    for (int i = 0; i < 16; i++) {
        const int flat = (i * 256 + t) * 16;
        const int r = flat >> 10, c = (flat >> 4) & 63;
        int gr = row0 + r; if (gr >= M) gr = M - 1;
        const void* g = A + (size_t)gr * 512 + ((c ^ (r & 7)) << 3);
        void* l = (void*)((char*)&As[0] + (size_t)(i * 256 + wave * 64) * 16);
        gload_lds16(g, l);
    }
    __syncthreads();

    f32x4 acc[4][2];
#pragma unroll
    for (int a = 0; a < 4; a++)
#pragma unroll
        for (int b = 0; b < 2; b++) acc[a][b] = (f32x4){0.f, 0.f, 0.f, 0.f};

#pragma unroll
    for (int kk = 0; kk < 16; kk++) {
        bf16x8 af[4];
#pragma unroll
        for (int fm = 0; fm < 4; fm++) {
            const int r = fm * 16 + lr;
            const int c = (kk * 4 + lk) ^ (r & 7);
            af[fm] = *reinterpret_cast<const bf16x8*>(&As[r * 512 + c * 8]);
        }
#pragma unroll
        for (int fm = 0; fm < 4; fm++)
#pragma unroll
            for (int fn = 0; fn < 2; fn++)
                acc[fm][fn] = __builtin_amdgcn_mfma_f32_16x16x32_bf16(
                    Bf[kk][fn], af[fm], acc[fm][fn], 0, 0, 0);
    }

#pragma unroll
    for (int fm = 0; fm < 4; fm++) {
        const int row = row0 + fm * 16 + lr;
        if (row < M) {
#pragma unroll
            for (int fn = 0; fn < 2; fn++) {
                const int col0 = wave * 32 + fn * 16 + lk * 4;
                const size_t off = (size_t)row * 128 + col0;
                f32x4 vv = acc[fm][fn] + bs[fn];
                vv += *reinterpret_cast<const f32x4*>(f_h + off);
                *reinterpret_cast<f32x4*>(f_h + off) = vv;
                uint2 o; o.x = pack2(vv[0], vv[1]); o.y = pack2(vv[2], vv[3]);
                *reinterpret_cast<uint2*>(f_hb + off) = o;
            }
        }
    }
}

// ---------------------------------------------------------------------------
// gemm_mrelu: h' = relu(x + (f_hb[src[e]] - h[e^1]) @ Wm + b). Reg-staged.
// ---------------------------------------------------------------------------
__global__ __launch_bounds__(256, 3) void gemm_mrelu(
    const unsigned short* __restrict__ f_hb, const unsigned short* __restrict__ h,
    const int* __restrict__ src, const unsigned short* __restrict__ WT,
    const float* __restrict__ bias, const unsigned short* __restrict__ resx,
    unsigned short* __restrict__ out, int E, int ntiles)
{
    __shared__ __align__(16) unsigned short As[2][64 * 128];

    const int t = threadIdx.x, wave = t >> 6, lane = t & 63;
    const int lr = lane & 15, lk = lane >> 4;

    bf16x8 Bf[4][2];
    f32x4 bs[2];
#pragma unroll
    for (int fn = 0; fn < 2; fn++) {
        const int col0 = wave * 32 + fn * 16 + lk * 4;
        bs[fn] = *reinterpret_cast<const f32x4*>(bias + col0);
        const int n = wave * 32 + fn * 16 + lr;
#pragma unroll
        for (int kk = 0; kk < 4; kk++)
            Bf[kk][fn] = *reinterpret_cast<const bf16x8*>(WT + n * 128 + kk * 32 + lk * 8);
    }

    uint4 Lh[4], Lf[4];
    auto load_t = [&](int row0) {
#pragma unroll
        for (int i = 0; i < 4; i++) {
            const int flat = (wave * 4 + i) * 1024 + lane * 16;
            const int r = flat >> 8, c = (flat >> 4) & 15;
            int e = row0 + r; if (e >= E) e = E - 1;
            Lh[i] = *reinterpret_cast<const uint4*>(h + (size_t)(e ^ 1) * 128 + c * 8);
            const int se = src[e];
            Lf[i] = *reinterpret_cast<const uint4*>(f_hb + (size_t)se * 128 + c * 8);
        }
    };
    auto write_t = [&](int buf) {
#pragma unroll
        for (int i = 0; i < 4; i++) {
            const int flat = (wave * 4 + i) * 1024 + lane * 16;
            const int r = flat >> 8, c = (flat >> 4) & 15;
            uint4 d;
            d.x = pksub(Lf[i].x, Lh[i].x); d.y = pksub(Lf[i].y, Lh[i].y);
            d.z = pksub(Lf[i].z, Lh[i].z); d.w = pksub(Lf[i].w, Lh[i].w);
            *reinterpret_cast<uint4*>(&As[buf][r * 128 + ((c ^ (r & 7)) << 3)]) = d;
        }
    };

    int tt = blockIdx.x;
    if (tt >= ntiles) return;
    load_t(tt * 64);
    write_t(0);
    int cur = 0;
    __syncthreads();

    for (; tt < ntiles; tt += gridDim.x) {
        const int nxt = tt + gridDim.x;
        if (nxt < ntiles) load_t(nxt * 64);

        f32x4 acc[4][2];
#pragma unroll
        for (int a = 0; a < 4; a++)
#pragma unroll
            for (int b = 0; b < 2; b++) acc[a][b] = (f32x4){0.f, 0.f, 0.f, 0.f};

#pragma unroll
        for (int kk = 0; kk < 4; kk++) {
            bf16x8 af[4];
#pragma unroll
            for (int fm = 0; fm < 4; fm++) {
                const int r = fm * 16 + lr;
                const int c = (kk * 4 + lk) ^ (r & 7);
                af[fm] = *reinterpret_cast<const bf16x8*>(&As[cur][r * 128 + c * 8]);
            }
#pragma unroll
            for (int fm = 0; fm < 4; fm++)
#pragma unroll
                for (int fn = 0; fn < 2; fn++)
                    acc[fm][fn] = __builtin_amdgcn_mfma_f32_16x16x32_bf16(
                        Bf[kk][fn], af[fm], acc[fm][fn], 0, 0, 0);
        }

        const int row0 = tt * 64;
#pragma unroll
        for (int fm = 0; fm < 4; fm++) {
            const int row = row0 + fm * 16 + lr;
            if (row < E) {
#pragma unroll
                for (int fn = 0; fn < 2; fn++) {
                    const int col0 = wave * 32 + fn * 16 + lk * 4;
                    const size_t off = (size_t)row * 128 + col0;
                    f32x4 vv = acc[fm][fn] + bs[fn];
                    uint2 rb = *reinterpret_cast<const uint2*>(resx + off);
                    vv[0] += bf2f((unsigned short)(rb.x & 0xffff));
                    vv[1] += bf2f((unsigned short)(rb.x >> 16));
                    vv[2] += bf2f((unsigned short)(rb.y & 0xffff));
                    vv[3] += bf2f((unsigned short)(rb.y >> 16));
                    vv[0] = fmaxf(vv[0], 0.f); vv[1] = fmaxf(vv[1], 0.f);
                    vv[2] = fmaxf(vv[2], 0.f); vv[3] = fmaxf(vv[3], 0.f);
                    uint2 o; o.x = pack2(vv[0], vv[1]); o.y = pack2(vv[2], vv[3]);
                    *reinterpret_cast<uint2*>(out + off) = o;
                }
            }
        }

        if (nxt < ntiles) write_t(cur ^ 1);
        __syncthreads();
        cur ^= 1;
    }
}

// ---------------------------------------------------------------------------
// CSR build
// ---------------------------------------------------------------------------
__global__ void hist_kernel(const int* __restrict__ dst, int* __restrict__ deg, int E_) {
    int e = blockIdx.x * 256 + threadIdx.x;
    if (e < E_) atomicAdd(&deg[dst[e]], 1);
}

__global__ __launch_bounds__(1024) void scan_kernel(
    const int* __restrict__ deg, int* __restrict__ rowptr,
    int* __restrict__ cursor, int N_)
{
    __shared__ int part[1024];
    const int t = threadIdx.x;
    const int chunk = (N_ + 1023) >> 10;
    const int base = t * chunk;
    int s = 0;
    for (int i = 0; i < chunk; i++) {
        int idx = base + i;
        if (idx < N_) s += deg[idx];
    }
    part[t] = s;
    __syncthreads();
    for (int off = 1; off < 1024; off <<= 1) {
        int v = (t >= off) ? part[t - off] : 0;
        __syncthreads();
        part[t] += v;
        __syncthreads();
    }
    int run = (t == 0) ? 0 : part[t - 1];
    for (int i = 0; i < chunk; i++) {
        int idx = base + i;
        if (idx < N_) {
            rowptr[idx] = run;
            cursor[idx] = run;
            run += deg[idx];
        }
    }
    if (t == 1023) rowptr[N_] = part[1023];
}

__global__ void scatter_kernel(const int* __restrict__ dst, int* __restrict__ cursor,
                               int* __restrict__ eidx, int E_) {
    int e = blockIdx.x * 256 + threadIdx.x;
    if (e >= E_) return;
    int pos = atomicAdd(&cursor[dst[e]], 1);
    eidx[pos] = e;
}

// ---------------------------------------------------------------------------
// attn_fused: per node (1 wave): scores via qkt-row dot h_e (full-wave
// reduction per head), online softmax, accumulate normalized weighted
// mailbox whm[n][hd*128+d] = sum_e p*h_e[d] / sum_e p.  Lane: dims 2l,2l+1.
// ---------------------------------------------------------------------------
__global__ __launch_bounds__(256) void attn_fused(
    const unsigned short* __restrict__ qkt, const unsigned short* __restrict__ h,
    const int* __restrict__ rowptr, const int* __restrict__ eidx,
    unsigned short* __restrict__ whm, int N_)
{
    const int n = blockIdx.x * 4 + (threadIdx.x >> 6);
    if (n >= N_) return;
    const int lane = threadIdx.x & 63;

    const int beg = rowptr[n], end = rowptr[n + 1];

    float qk0[4], qk1[4];
#pragma unroll
    for (int hd = 0; hd < 4; hd++) {
        unsigned u = *(const unsigned*)(qkt + (size_t)n * 512 + hd * 128 + lane * 2);
        qk0[hd] = bf2f((unsigned short)(u & 0xffff));
        qk1[hd] = bf2f((unsigned short)(u >> 16));
    }

    if (beg == end) {
#pragma unroll
        for (int hd = 0; hd < 4; hd++)
            *(unsigned*)(whm + (size_t)n * 512 + hd * 128 + lane * 2) = 0;
        return;
    }

    float m[4], l[4], a0[4], a1[4];
#pragma unroll
    for (int hd = 0; hd < 4; hd++) { m[hd] = -3.0e38f; l[hd] = 0.f; a0[hd] = 0.f; a1[hd] = 0.f; }

    unsigned hv = *(const unsigned*)(h + (size_t)eidx[beg] * 128 + lane * 2);

    for (int i = beg; i < end; i++) {
        unsigned hcur = hv;
        if (i + 1 < end)
            hv = *(const unsigned*)(h + (size_t)eidx[i + 1] * 128 + lane * 2);
        const float f0 = bf2f((unsigned short)(hcur & 0xffff));
        const float f1 = bf2f((unsigned short)(hcur >> 16));

        float part[4];
#pragma unroll
        for (int hd = 0; hd < 4; hd++) part[hd] = f0 * qk0[hd] + f1 * qk1[hd];
#pragma unroll
        for (int off = 1; off < 64; off <<= 1) {
#pragma unroll
            for (int hd = 0; hd < 4; hd++)
                part[hd] += __shfl_xor(part[hd], off, 64);
        }
#pragma unroll
        for (int hd = 0; hd < 4; hd++) {
            const float s = part[hd] * 0.17677669529663687f;  // 1/sqrt(32)
            const float mn = fmaxf(m[hd], s);
            const float sc = __expf(m[hd] - mn);
            const float pp = __expf(s - mn);
            l[hd] = l[hd] * sc + pp;
            a0[hd] = a0[hd] * sc + pp * f0;
            a1[hd] = a1[hd] * sc + pp * f1;
            m[hd] = mn;
        }
    }
#pragma unroll
    for (int hd = 0; hd < 4; hd++) {
        const float rl = 1.f / l[hd];
        *(unsigned*)(whm + (size_t)n * 512 + hd * 128 + lane * 2) =
            pack2(a0[hd] * rl, a1[hd] * rl);
    }
}

// mail[n] = sum over incoming edges of h[e]  (gathered via eidx)
__global__ __launch_bounds__(256) void mail_csr(
    const unsigned short* __restrict__ h,
    const int* __restrict__ rowptr, const int* __restrict__ eidx,
    unsigned short* __restrict__ mailb, int N_)
{
    const int n = blockIdx.x * 4 + (threadIdx.x >> 6);
    if (n >= N_) return;
    const int lane = threadIdx.x & 63;

    const int beg = rowptr[n], end = rowptr[n + 1];
    float a0 = 0.f, a1 = 0.f;
    if (beg < end) {
        long e = eidx[beg];
        unsigned hc = *(const unsigned*)(h + e * 128 + lane * 2);
        for (int i = beg; i < end; i++) {
            unsigned hcur = hc;
            if (i + 1 < end) {
                long e2 = eidx[i + 1];
                hc = *(const unsigned*)(h + e2 * 128 + lane * 2);
            }
            a0 += bf2f((unsigned short)(hcur & 0xffff));
            a1 += bf2f((unsigned short)(hcur >> 16));
        }
    }
    *(unsigned*)(mailb + (size_t)n * 128 + lane * 2) = pack2(a0, a1);
}

// ---------------------------------------------------------------------------
// Precompute kernels
// ---------------------------------------------------------------------------
struct W5 { const float* p[5]; };

__global__ void cvt_wT(W5 w, unsigned short* __restrict__ out) {
    const float* src = w.p[blockIdx.x];
    unsigned short* dst = out + (size_t)blockIdx.x * 16384;
    for (int idx = threadIdx.x; idx < 16384; idx += 256) {
        const int k = idx >> 7, n = idx & 127;
        dst[n * 128 + k] = f2bf(src[idx]);
    }
}

// McatT[oc][a] = sum_jj Wq[a][hd*32+jj] * Wk[ip][hd*32+jj]; oc = hd*128+ip
// cbias[oc]   = sum_jj bq[hd*32+jj] * Wk[ip][hd*32+jj]
__global__ void mcat_kernel(const float* __restrict__ Wq, const float* __restrict__ Wk,
                            const float* __restrict__ bq,
                            unsigned short* __restrict__ McatT, float* __restrict__ cbias) {
    const int oc = blockIdx.x;            // 0..511
    const int hd = oc >> 7, ip = oc & 127;
    const int a = threadIdx.x;            // 0..127
    const float* wk = Wk + ip * 128 + hd * 32;
    const float* wq = Wq + a * 128 + hd * 32;
    float s = 0.f;
    for (int jj = 0; jj < 32; jj++) s += wq[jj] * wk[jj];
    McatT[(size_t)oc * 128 + a] = f2bf(s);
    if (a == 0) {
        float c = 0.f;
        for (int jj = 0; jj < 32; jj++) c += bq[hd * 32 + jj] * wk[jj];
        cbias[oc] = c;
    }
}

// PcatT[j][hd*128+i] = sum_cc Wv[i][hd*32+cc] * Wo[hd*32+cc][j]
__global__ void pcat_kernel(const float* __restrict__ Wv, const float* __restrict__ Wo,
                            unsigned short* __restrict__ PcatT) {
    const int j = blockIdx.x;             // 0..127
    const int k = threadIdx.x;            // 0..511
    const int hd = k >> 7, i = k & 127;
    float s = 0.f;
    for (int cc = 0; cc < 32; cc++)
        s += Wv[i * 128 + hd * 32 + cc] * Wo[(hd * 32 + cc) * 128 + j];
    PcatT[(size_t)j * 512 + k] = f2bf(s);
}

// bias2[j] = sum_c bv[c]*Wo[c][j] + bo[j]
__global__ void bias2_kernel(const float* __restrict__ bv, const float* __restrict__ Wo,
                             const float* __restrict__ bo, float* __restrict__ bias2) {
    const int j = threadIdx.x;
    if (j >= 128) return;
    float s = 0.f;
    for (int c = 0; c < 128; c++) s += bv[c] * Wo[c * 128 + j];
    bias2[j] = s + bo[j];
}

__global__ void cvt_bf16(const float* __restrict__ in, unsigned short* __restrict__ out, long n4) {
    long i = (long)blockIdx.x * 256 + threadIdx.x;
    if (i >= n4) return;
    float4 v = reinterpret_cast<const float4*>(in)[i];
    ushort4 o;
    o.x = f2bf(v.x); o.y = f2bf(v.y); o.z = f2bf(v.z); o.w = f2bf(v.w);
    reinterpret_cast<ushort4*>(out)[i] = o;
}

__global__ void prep_f(const float* __restrict__ f, unsigned short* __restrict__ fb,
                       float* __restrict__ f_h, int n4) {
    int i = blockIdx.x * 256 + threadIdx.x;
    if (i >= n4) return;
    float4 v = reinterpret_cast<const float4*>(f)[i];
    reinterpret_cast<float4*>(f_h)[i] = v;
    ushort4 o;
    o.x = f2bf(v.x); o.y = f2bf(v.y); o.z = f2bf(v.z); o.w = f2bf(v.w);
    reinterpret_cast<ushort4*>(fb)[i] = o;
}

// ---------------------------------------------------------------------------
extern "C" void kernel_launch(void* const* d_in, const int* in_sizes, int n_in,
                              void* d_out, int out_size, void* d_ws, size_t ws_size,
                              hipStream_t stream)
{
    const float* f      = (const float*)d_in[0];
    const float* x      = (const float*)d_in[1];
    const int*   src    = (const int*)d_in[2];
    const int*   dst    = (const int*)d_in[3];
    const float* Wq     = (const float*)d_in[4];
    const float* bq     = (const float*)d_in[5];
    const float* Wk     = (const float*)d_in[6];
    const float* bk     = (const float*)d_in[7];   // cancels in softmax
    const float* Wv     = (const float*)d_in[8];
    const float* bv     = (const float*)d_in[9];
    const float* Wo     = (const float*)d_in[10];
    const float* bo     = (const float*)d_in[11];
    const float* W_mp   = (const float*)d_in[12];
    const float* b_mp   = (const float*)d_in[13];
    const float* W_last = (const float*)d_in[14];
    const float* b_last = (const float*)d_in[15];
    (void)bk;

    const int N = in_sizes[0] / 128;
    const int E = in_sizes[1] / 128;

    char* p = (char*)d_ws;
    auto take = [&](size_t bytes) { char* r = p; p += (bytes + 255) & ~(size_t)255; return r; };
    unsigned short* w5T   = (unsigned short*)take(5 * 16384 * 2);
    unsigned short* McatT = (unsigned short*)take(512 * 128 * 2);
    unsigned short* PcatT = (unsigned short*)take(128 * 512 * 2);
    float* cbias  = (float*)take(512 * 4);
    float* bias2  = (float*)take(128 * 4);
    unsigned short* xb    = (unsigned short*)take((size_t)E * 128 * 2);
    unsigned short* h1    = (unsigned short*)take((size_t)E * 128 * 2);
    unsigned short* h2    = (unsigned short*)take((size_t)E * 128 * 2);
    unsigned short* fb    = (unsigned short*)take((size_t)N * 128 * 2);
    unsigned short* f_hb  = (unsigned short*)take((size_t)N * 128 * 2);
    unsigned short* qkt   = (unsigned short*)take((size_t)N * 512 * 2);
    unsigned short* whm   = (unsigned short*)take((size_t)N * 512 * 2);
    unsigned short* mailb = (unsigned short*)take((size_t)N * 128 * 2);
    float* f_h    = (float*)take((size_t)N * 128 * 4);
    int* deg      = (int*)take((size_t)N * 4);
    int* rowptr   = (int*)take((size_t)(N + 1) * 4);
    int* cursor   = (int*)take((size_t)N * 4);
    int* eidx     = (int*)take((size_t)E * 4);

    const unsigned short* Wm0T = w5T + 0 * 16384;
    const unsigned short* Wm1T = w5T + 1 * 16384;
    const unsigned short* WL0T = w5T + 2 * 16384;
    const unsigned short* WL1T = w5T + 3 * 16384;
    const unsigned short* WL2T = w5T + 4 * 16384;

    W5 w5;
    w5.p[0] = W_mp; w5.p[1] = W_mp + 16384;
    w5.p[2] = W_last; w5.p[3] = W_last + 16384; w5.p[4] = W_last + 32768;

    // --- setup: weights, folded matrices, bf16 copies, CSR ---
    cvt_wT<<<5, 256, 0, stream>>>(w5, w5T);
    mcat_kernel<<<512, 128, 0, stream>>>(Wq, Wk, bq, McatT, cbias);
    pcat_kernel<<<128, 512, 0, stream>>>(Wv, Wo, PcatT);
    bias2_kernel<<<1, 128, 0, stream>>>(bv, Wo, bo, bias2);
    cvt_bf16<<<(int)(((long)E * 32 + 255) / 256), 256, 0, stream>>>(x, xb, (long)E * 32);
    prep_f<<<(N * 32 + 255) / 256, 256, 0, stream>>>(f, fb, f_h, N * 32);

    hipMemsetAsync(deg, 0, (size_t)N * 4, stream);
    hist_kernel<<<(E + 255) / 256, 256, 0, stream>>>(dst, deg, E);
    scan_kernel<<<1, 1024, 0, stream>>>(deg, rowptr, cursor, N);
    scatter_kernel<<<(E + 255) / 256, 256, 0, stream>>>(dst, cursor, eidx, E);

    const int ntN = (N + 63) / 64;
    const int ntE = (E + 63) / 64;
    const int gNode = (N + 3) / 4;

    const unsigned short* hc = xb;
    unsigned short* houts[2] = { h1, h2 };
    for (int it = 0; it < 2; it++) {
        const unsigned short* fh_in = (it == 0) ? fb : f_hb;
        // qkt = f_h @ Mcat + c   (bf16 [N,512])
        gemm_q512<<<ntN, 512, 0, stream>>>(fh_in, McatT, cbias, qkt, N);
        // fused attention -> normalized weighted mailbox whm (bf16 [N,512])
        attn_fused<<<gNode, 256, 0, stream>>>(qkt, hc, rowptr, eidx, whm, N);
        // f_h += whm @ Pcat + bias2 ; f_hb = bf16(f_h)
        gemm_k512<<<ntN, 256, 0, stream>>>(whm, PcatT, bias2, f_h, f_hb, N);
        // h' = relu(x + (f_hb[src] - rev(h)) @ Wm + b)
        gemm_mrelu<<<768, 256, 0, stream>>>(
            f_hb, hc, src, (it == 0) ? Wm0T : Wm1T, b_mp + (size_t)it * 128,
            xb, houts[it], E, ntE);
        hc = houts[it];
    }

    // mail = segment_sum(h, dst)
    mail_csr<<<gNode, 256, 0, stream>>>(hc, rowptr, eidx, mailb, N);

    // out = mail@WL0 + f_h@WL1 + f@WL2 + b_last
    gemm_s<0, false, false><<<ntN, 256, 0, stream>>>(
        mailb, WL0T, b_last, nullptr, (float*)d_out, nullptr, N, ntN);
    gemm_s<1, false, false><<<ntN, 256, 0, stream>>>(
        f_hb, WL1T, nullptr, d_out, (float*)d_out, nullptr, N, ntN);
    gemm_s<1, false, false><<<ntN, 256, 0, stream>>>(
        fb, WL2T, nullptr, d_out, (float*)d_out, nullptr, N, ntN);
}

// Round 6
// 555.450 us; speedup vs baseline: 4.3302x; 1.2753x over previous
//
#include <hip/hip_runtime.h>
#include <hip/hip_bf16.h>

typedef __attribute__((ext_vector_type(8))) short bf16x8;
typedef __attribute__((ext_vector_type(4))) float f32x4;

__device__ __forceinline__ unsigned short f2bf(float f) {
    unsigned u = __float_as_uint(f);
    unsigned r = (u + 0x7FFFu + ((u >> 16) & 1u)) >> 16;  // RNE
    return (unsigned short)r;
}
__device__ __forceinline__ float bf2f(unsigned short b) {
    return __uint_as_float(((unsigned)b) << 16);
}
__device__ __forceinline__ unsigned pack2(float a, float b) {
    return (unsigned)f2bf(a) | ((unsigned)f2bf(b) << 16);
}
__device__ __forceinline__ unsigned pksub(unsigned a, unsigned b) {
    float r0 = bf2f((unsigned short)(a & 0xffff)) - bf2f((unsigned short)(b & 0xffff));
    float r1 = bf2f((unsigned short)(a >> 16))    - bf2f((unsigned short)(b >> 16));
    return pack2(r0, r1);
}
#define EXP2(x) __builtin_amdgcn_exp2f(x)

__device__ __forceinline__ void gload_lds16(const void* g, void* l) {
    __builtin_amdgcn_global_load_lds(
        (const __attribute__((address_space(1))) unsigned int*)g,
        (__attribute__((address_space(3))) unsigned int*)l,
        16, 0, 0);
}

// ---------------------------------------------------------------------------
// gemm_s: out[M x 128] = A[M x 128](bf16) @ W + bias (+res). 64-row tiles,
// 256 thr (4 waves x 32 cols). WT bf16 [n][k]; B in VGPRs. Persistent.
// ---------------------------------------------------------------------------
template<int RES, bool OUT_BF16, bool OUT2>
__global__ __launch_bounds__(256, 4) void gemm_s(
    const unsigned short* __restrict__ A, const unsigned short* __restrict__ WT,
    const float* __restrict__ bias, const void* res,
    void* out, unsigned short* __restrict__ out2, int M, int ntiles)
{
    __shared__ __align__(16) unsigned short As[2][64 * 128];

    const int t = threadIdx.x, wave = t >> 6, lane = t & 63;
    const int lr = lane & 15, lk = lane >> 4;

    bf16x8 Bf[4][2];
    f32x4 bs[2];
#pragma unroll
    for (int fn = 0; fn < 2; fn++) {
        const int col0 = wave * 32 + fn * 16 + lk * 4;
        bs[fn] = bias ? *reinterpret_cast<const f32x4*>(bias + col0)
                      : (f32x4){0.f, 0.f, 0.f, 0.f};
        const int n = wave * 32 + fn * 16 + lr;
#pragma unroll
        for (int kk = 0; kk < 4; kk++)
            Bf[kk][fn] = *reinterpret_cast<const bf16x8*>(WT + n * 128 + kk * 32 + lk * 8);
    }

    auto stage = [&](int buf, int row0) {
#pragma unroll
        for (int i = 0; i < 4; i++) {
            const int flat = (wave * 4 + i) * 1024 + lane * 16;
            const int r = flat >> 8, c = (flat >> 4) & 15;
            int gr = row0 + r; if (gr >= M) gr = M - 1;
            const void* g = A + (size_t)gr * 128 + ((c ^ (r & 7)) << 3);
            void* l = (void*)((char*)&As[buf][0] + (size_t)(wave * 4 + i) * 1024);
            gload_lds16(g, l);
        }
    };

    int tt = blockIdx.x;
    if (tt >= ntiles) return;
    int cur = 0;
    stage(0, tt * 64);
    __syncthreads();

    for (; tt < ntiles; tt += gridDim.x) {
        const int nxt = tt + gridDim.x;
        if (nxt < ntiles) stage(cur ^ 1, nxt * 64);

        f32x4 acc[4][2];
#pragma unroll
        for (int a = 0; a < 4; a++)
#pragma unroll
            for (int b = 0; b < 2; b++) acc[a][b] = (f32x4){0.f, 0.f, 0.f, 0.f};

#pragma unroll
        for (int kk = 0; kk < 4; kk++) {
            bf16x8 af[4];
#pragma unroll
            for (int fm = 0; fm < 4; fm++) {
                const int r = fm * 16 + lr;
                const int c = (kk * 4 + lk) ^ (r & 7);
                af[fm] = *reinterpret_cast<const bf16x8*>(&As[cur][r * 128 + c * 8]);
            }
#pragma unroll
            for (int fm = 0; fm < 4; fm++)
#pragma unroll
                for (int fn = 0; fn < 2; fn++)
                    acc[fm][fn] = __builtin_amdgcn_mfma_f32_16x16x32_bf16(
                        Bf[kk][fn], af[fm], acc[fm][fn], 0, 0, 0);
        }

        const int row0 = tt * 64;
#pragma unroll
        for (int fm = 0; fm < 4; fm++) {
            const int row = row0 + fm * 16 + lr;
            if (row < M) {
#pragma unroll
                for (int fn = 0; fn < 2; fn++) {
                    const int col0 = wave * 32 + fn * 16 + lk * 4;
                    const size_t off = (size_t)row * 128 + col0;
                    f32x4 vv = acc[fm][fn] + bs[fn];
                    if (RES == 1)
                        vv += *reinterpret_cast<const f32x4*>((const float*)res + off);
                    if (OUT_BF16) {
                        uint2 o; o.x = pack2(vv[0], vv[1]); o.y = pack2(vv[2], vv[3]);
                        *reinterpret_cast<uint2*>((unsigned short*)out + off) = o;
                    } else {
                        *reinterpret_cast<f32x4*>((float*)out + off) = vv;
                    }
                    if (OUT2) {
                        uint2 o; o.x = pack2(vv[0], vv[1]); o.y = pack2(vv[2], vv[3]);
                        *reinterpret_cast<uint2*>(out2 + off) = o;
                    }
                }
            }
        }
        __syncthreads();
        cur ^= 1;
    }
}

// ---------------------------------------------------------------------------
// gemm_q512: qkt[M x 512](bf16) = A[M x 128](bf16) @ McatT + cbias.
// ---------------------------------------------------------------------------
__global__ __launch_bounds__(512, 2) void gemm_q512(
    const unsigned short* __restrict__ A, const unsigned short* __restrict__ WT,
    const float* __restrict__ bias, unsigned short* __restrict__ out, int M)
{
    __shared__ __align__(16) unsigned short As[64 * 128];

    const int t = threadIdx.x, wave = t >> 6, lane = t & 63;
    const int lr = lane & 15, lk = lane >> 4;

    bf16x8 Bf[4][4];
    f32x4 bs[4];
#pragma unroll
    for (int fn = 0; fn < 4; fn++) {
        const int col0 = wave * 64 + fn * 16 + lk * 4;
        bs[fn] = *reinterpret_cast<const f32x4*>(bias + col0);
        const int n = wave * 64 + fn * 16 + lr;
#pragma unroll
        for (int kk = 0; kk < 4; kk++)
            Bf[kk][fn] = *reinterpret_cast<const bf16x8*>(WT + n * 128 + kk * 32 + lk * 8);
    }

    const int row0 = blockIdx.x * 64;
#pragma unroll
    for (int i = 0; i < 2; i++) {
        const int flat = (i * 512 + t) * 16;
        const int r = flat >> 8, c = (flat >> 4) & 15;
        int gr = row0 + r; if (gr >= M) gr = M - 1;
        const void* g = A + (size_t)gr * 128 + ((c ^ (r & 7)) << 3);
        void* l = (void*)((char*)&As[0] + (size_t)(i * 512 + wave * 64) * 16 + 0);
        gload_lds16(g, l);
    }
    __syncthreads();

    f32x4 acc[4][4];
#pragma unroll
    for (int a = 0; a < 4; a++)
#pragma unroll
        for (int b = 0; b < 4; b++) acc[a][b] = (f32x4){0.f, 0.f, 0.f, 0.f};

#pragma unroll
    for (int kk = 0; kk < 4; kk++) {
        bf16x8 af[4];
#pragma unroll
        for (int fm = 0; fm < 4; fm++) {
            const int r = fm * 16 + lr;
            const int c = (kk * 4 + lk) ^ (r & 7);
            af[fm] = *reinterpret_cast<const bf16x8*>(&As[r * 128 + c * 8]);
        }
#pragma unroll
        for (int fm = 0; fm < 4; fm++)
#pragma unroll
            for (int fn = 0; fn < 4; fn++)
                acc[fm][fn] = __builtin_amdgcn_mfma_f32_16x16x32_bf16(
                    Bf[kk][fn], af[fm], acc[fm][fn], 0, 0, 0);
    }

#pragma unroll
    for (int fm = 0; fm < 4; fm++) {
        const int row = row0 + fm * 16 + lr;
        if (row < M) {
#pragma unroll
            for (int fn = 0; fn < 4; fn++) {
                const int col0 = wave * 64 + fn * 16 + lk * 4;
                f32x4 vv = acc[fm][fn] + bs[fn];
                uint2 o; o.x = pack2(vv[0], vv[1]); o.y = pack2(vv[2], vv[3]);
                *reinterpret_cast<uint2*>(out + (size_t)row * 512 + col0) = o;
            }
        }
    }
}

// ---------------------------------------------------------------------------
// gemm_k512: f_h[M x 128](fp32) += A[M x 512](bf16) @ PcatT + bias2;
// also emits f_hb bf16.
// ---------------------------------------------------------------------------
__global__ __launch_bounds__(256, 2) void gemm_k512(
    const unsigned short* __restrict__ A, const unsigned short* __restrict__ WT,
    const float* __restrict__ bias, float* __restrict__ f_h,
    unsigned short* __restrict__ f_hb, int M)
{
    __shared__ __align__(16) unsigned short As[64 * 512];  // 64KB

    const int t = threadIdx.x, wave = t >> 6, lane = t & 63;
    const int lr = lane & 15, lk = lane >> 4;

    bf16x8 Bf[16][2];
    f32x4 bs[2];
#pragma unroll
    for (int fn = 0; fn < 2; fn++) {
        const int col0 = wave * 32 + fn * 16 + lk * 4;
        bs[fn] = *reinterpret_cast<const f32x4*>(bias + col0);
        const int n = wave * 32 + fn * 16 + lr;
#pragma unroll
        for (int kk = 0; kk < 16; kk++)
            Bf[kk][fn] = *reinterpret_cast<const bf16x8*>(WT + n * 512 + kk * 32 + lk * 8);
    }

    const int row0 = blockIdx.x * 64;
#pragma unroll
    for (int i = 0; i < 16; i++) {
        const int flat = (i * 256 + t) * 16;
        const int r = flat >> 10, c = (flat >> 4) & 63;
        int gr = row0 + r; if (gr >= M) gr = M - 1;
        const void* g = A + (size_t)gr * 512 + ((c ^ (r & 7)) << 3);
        void* l = (void*)((char*)&As[0] + (size_t)(i * 256 + wave * 64) * 16);
        gload_lds16(g, l);
    }
    __syncthreads();

    f32x4 acc[4][2];
#pragma unroll
    for (int a = 0; a < 4; a++)
#pragma unroll
        for (int b = 0; b < 2; b++) acc[a][b] = (f32x4){0.f, 0.f, 0.f, 0.f};

#pragma unroll
    for (int kk = 0; kk < 16; kk++) {
        bf16x8 af[4];
#pragma unroll
        for (int fm = 0; fm < 4; fm++) {
            const int r = fm * 16 + lr;
            const int c = (kk * 4 + lk) ^ (r & 7);
            af[fm] = *reinterpret_cast<const bf16x8*>(&As[r * 512 + c * 8]);
        }
#pragma unroll
        for (int fm = 0; fm < 4; fm++)
#pragma unroll
            for (int fn = 0; fn < 2; fn++)
                acc[fm][fn] = __builtin_amdgcn_mfma_f32_16x16x32_bf16(
                    Bf[kk][fn], af[fm], acc[fm][fn], 0, 0, 0);
    }

#pragma unroll
    for (int fm = 0; fm < 4; fm++) {
        const int row = row0 + fm * 16 + lr;
        if (row < M) {
#pragma unroll
            for (int fn = 0; fn < 2; fn++) {
                const int col0 = wave * 32 + fn * 16 + lk * 4;
                const size_t off = (size_t)row * 128 + col0;
                f32x4 vv = acc[fm][fn] + bs[fn];
                vv += *reinterpret_cast<const f32x4*>(f_h + off);
                *reinterpret_cast<f32x4*>(f_h + off) = vv;
                uint2 o; o.x = pack2(vv[0], vv[1]); o.y = pack2(vv[2], vv[3]);
                *reinterpret_cast<uint2*>(f_hb + off) = o;
            }
        }
    }
}

// ---------------------------------------------------------------------------
// gemm_mrelu: h' = relu(x + (f_hb[src[e]] - h[e^1]) @ Wm + b). Reg-staged.
// ---------------------------------------------------------------------------
__global__ __launch_bounds__(256, 3) void gemm_mrelu(
    const unsigned short* __restrict__ f_hb, const unsigned short* __restrict__ h,
    const int* __restrict__ src, const unsigned short* __restrict__ WT,
    const float* __restrict__ bias, const unsigned short* __restrict__ resx,
    unsigned short* __restrict__ out, int E, int ntiles)
{
    __shared__ __align__(16) unsigned short As[2][64 * 128];

    const int t = threadIdx.x, wave = t >> 6, lane = t & 63;
    const int lr = lane & 15, lk = lane >> 4;

    bf16x8 Bf[4][2];
    f32x4 bs[2];
#pragma unroll
    for (int fn = 0; fn < 2; fn++) {
        const int col0 = wave * 32 + fn * 16 + lk * 4;
        bs[fn] = *reinterpret_cast<const f32x4*>(bias + col0);
        const int n = wave * 32 + fn * 16 + lr;
#pragma unroll
        for (int kk = 0; kk < 4; kk++)
            Bf[kk][fn] = *reinterpret_cast<const bf16x8*>(WT + n * 128 + kk * 32 + lk * 8);
    }

    uint4 Lh[4], Lf[4];
    auto load_t = [&](int row0) {
#pragma unroll
        for (int i = 0; i < 4; i++) {
            const int flat = (wave * 4 + i) * 1024 + lane * 16;
            const int r = flat >> 8, c = (flat >> 4) & 15;
            int e = row0 + r; if (e >= E) e = E - 1;
            Lh[i] = *reinterpret_cast<const uint4*>(h + (size_t)(e ^ 1) * 128 + c * 8);
            const int se = src[e];
            Lf[i] = *reinterpret_cast<const uint4*>(f_hb + (size_t)se * 128 + c * 8);
        }
    };
    auto write_t = [&](int buf) {
#pragma unroll
        for (int i = 0; i < 4; i++) {
            const int flat = (wave * 4 + i) * 1024 + lane * 16;
            const int r = flat >> 8, c = (flat >> 4) & 15;
            uint4 d;
            d.x = pksub(Lf[i].x, Lh[i].x); d.y = pksub(Lf[i].y, Lh[i].y);
            d.z = pksub(Lf[i].z, Lh[i].z); d.w = pksub(Lf[i].w, Lh[i].w);
            *reinterpret_cast<uint4*>(&As[buf][r * 128 + ((c ^ (r & 7)) << 3)]) = d;
        }
    };

    int tt = blockIdx.x;
    if (tt >= ntiles) return;
    load_t(tt * 64);
    write_t(0);
    int cur = 0;
    __syncthreads();

    for (; tt < ntiles; tt += gridDim.x) {
        const int nxt = tt + gridDim.x;
        if (nxt < ntiles) load_t(nxt * 64);

        f32x4 acc[4][2];
#pragma unroll
        for (int a = 0; a < 4; a++)
#pragma unroll
            for (int b = 0; b < 2; b++) acc[a][b] = (f32x4){0.f, 0.f, 0.f, 0.f};

#pragma unroll
        for (int kk = 0; kk < 4; kk++) {
            bf16x8 af[4];
#pragma unroll
            for (int fm = 0; fm < 4; fm++) {
                const int r = fm * 16 + lr;
                const int c = (kk * 4 + lk) ^ (r & 7);
                af[fm] = *reinterpret_cast<const bf16x8*>(&As[cur][r * 128 + c * 8]);
            }
#pragma unroll
            for (int fm = 0; fm < 4; fm++)
#pragma unroll
                for (int fn = 0; fn < 2; fn++)
                    acc[fm][fn] = __builtin_amdgcn_mfma_f32_16x16x32_bf16(
                        Bf[kk][fn], af[fm], acc[fm][fn], 0, 0, 0);
        }

        const int row0 = tt * 64;
#pragma unroll
        for (int fm = 0; fm < 4; fm++) {
            const int row = row0 + fm * 16 + lr;
            if (row < E) {
#pragma unroll
                for (int fn = 0; fn < 2; fn++) {
                    const int col0 = wave * 32 + fn * 16 + lk * 4;
                    const size_t off = (size_t)row * 128 + col0;
                    f32x4 vv = acc[fm][fn] + bs[fn];
                    uint2 rb = *reinterpret_cast<const uint2*>(resx + off);
                    vv[0] += bf2f((unsigned short)(rb.x & 0xffff));
                    vv[1] += bf2f((unsigned short)(rb.x >> 16));
                    vv[2] += bf2f((unsigned short)(rb.y & 0xffff));
                    vv[3] += bf2f((unsigned short)(rb.y >> 16));
                    vv[0] = fmaxf(vv[0], 0.f); vv[1] = fmaxf(vv[1], 0.f);
                    vv[2] = fmaxf(vv[2], 0.f); vv[3] = fmaxf(vv[3], 0.f);
                    uint2 o; o.x = pack2(vv[0], vv[1]); o.y = pack2(vv[2], vv[3]);
                    *reinterpret_cast<uint2*>(out + off) = o;
                }
            }
        }

        if (nxt < ntiles) write_t(cur ^ 1);
        __syncthreads();
        cur ^= 1;
    }
}

// ---------------------------------------------------------------------------
// CSR build
// ---------------------------------------------------------------------------
__global__ void hist_kernel(const int* __restrict__ dst, int* __restrict__ deg, int E_) {
    int e = blockIdx.x * 256 + threadIdx.x;
    if (e < E_) atomicAdd(&deg[dst[e]], 1);
}

__global__ __launch_bounds__(1024) void scan_kernel(
    const int* __restrict__ deg, int* __restrict__ rowptr,
    int* __restrict__ cursor, int N_)
{
    __shared__ int part[1024];
    const int t = threadIdx.x;
    const int chunk = (N_ + 1023) >> 10;
    const int base = t * chunk;
    int s = 0;
    for (int i = 0; i < chunk; i++) {
        int idx = base + i;
        if (idx < N_) s += deg[idx];
    }
    part[t] = s;
    __syncthreads();
    for (int off = 1; off < 1024; off <<= 1) {
        int v = (t >= off) ? part[t - off] : 0;
        __syncthreads();
        part[t] += v;
        __syncthreads();
    }
    int run = (t == 0) ? 0 : part[t - 1];
    for (int i = 0; i < chunk; i++) {
        int idx = base + i;
        if (idx < N_) {
            rowptr[idx] = run;
            cursor[idx] = run;
            run += deg[idx];
        }
    }
    if (t == 1023) rowptr[N_] = part[1023];
}

__global__ void scatter_kernel(const int* __restrict__ dst, int* __restrict__ cursor,
                               int* __restrict__ eidx, int E_) {
    int e = blockIdx.x * 256 + threadIdx.x;
    if (e >= E_) return;
    int pos = atomicAdd(&cursor[dst[e]], 1);
    eidx[pos] = e;
}

// ---------------------------------------------------------------------------
// attn_fused v2: 1 wave per node; 4 edges in flight (16-lane groups).
// lane = g*16+s: group g owns edge beg+it*4+g, slot s owns dims 8s..8s+7.
// Scores pre-scaled to log2 units (fold in Mcat). Online softmax per group,
// then 2-step cross-group merge (shfl_xor 16/32). Group g writes head g.
// ---------------------------------------------------------------------------
__global__ __launch_bounds__(256) void attn_fused(
    const unsigned short* __restrict__ qkt, const unsigned short* __restrict__ h,
    const int* __restrict__ rowptr, const int* __restrict__ eidx,
    unsigned short* __restrict__ whm, int N_)
{
    const int n = blockIdx.x * 4 + (threadIdx.x >> 6);
    if (n >= N_) return;
    const int lane = threadIdx.x & 63;
    const int g = lane >> 4, s = lane & 15;

    const int beg = rowptr[n], end = rowptr[n + 1];
    unsigned short* outp = whm + (size_t)n * 512 + g * 128 + s * 8;
    if (beg == end) {
        *reinterpret_cast<uint2*>(outp) = make_uint2(0u, 0u);
        *reinterpret_cast<uint2*>(outp + 4) = make_uint2(0u, 0u);
        return;
    }

    // qk[hd][j]: head hd, dims s*8+j (same for all 4 groups — broadcast loads)
    float qk[4][8];
#pragma unroll
    for (int hd = 0; hd < 4; hd++) {
        uint4 u = *reinterpret_cast<const uint4*>(qkt + (size_t)n * 512 + hd * 128 + s * 8);
        qk[hd][0] = bf2f((unsigned short)(u.x & 0xffff)); qk[hd][1] = bf2f((unsigned short)(u.x >> 16));
        qk[hd][2] = bf2f((unsigned short)(u.y & 0xffff)); qk[hd][3] = bf2f((unsigned short)(u.y >> 16));
        qk[hd][4] = bf2f((unsigned short)(u.z & 0xffff)); qk[hd][5] = bf2f((unsigned short)(u.z >> 16));
        qk[hd][6] = bf2f((unsigned short)(u.w & 0xffff)); qk[hd][7] = bf2f((unsigned short)(u.w >> 16));
    }

    float m[4], l[4], a[4][8];
#pragma unroll
    for (int hd = 0; hd < 4; hd++) {
        m[hd] = -3.0e38f; l[hd] = 0.f;
#pragma unroll
        for (int j = 0; j < 8; j++) a[hd][j] = 0.f;
    }

    const int T = (end - beg + 3) >> 2;
    int idx = beg + g;
    uint4 hv = make_uint4(0u, 0u, 0u, 0u);
    if (idx < end) hv = *reinterpret_cast<const uint4*>(h + (size_t)eidx[idx] * 128 + s * 8);

    for (int it = 0; it < T; it++) {
        const uint4 hc = hv;
        const bool valid = (idx < end);
        const int nidx = idx + 4;
        if (nidx < end) hv = *reinterpret_cast<const uint4*>(h + (size_t)eidx[nidx] * 128 + s * 8);
        idx = nidx;

        float hf[8];
        hf[0] = bf2f((unsigned short)(hc.x & 0xffff)); hf[1] = bf2f((unsigned short)(hc.x >> 16));
        hf[2] = bf2f((unsigned short)(hc.y & 0xffff)); hf[3] = bf2f((unsigned short)(hc.y >> 16));
        hf[4] = bf2f((unsigned short)(hc.z & 0xffff)); hf[5] = bf2f((unsigned short)(hc.z >> 16));
        hf[6] = bf2f((unsigned short)(hc.w & 0xffff)); hf[7] = bf2f((unsigned short)(hc.w >> 16));

        float part[4];
#pragma unroll
        for (int hd = 0; hd < 4; hd++) {
            float pp = 0.f;
#pragma unroll
            for (int j = 0; j < 8; j++) pp += qk[hd][j] * hf[j];
            part[hd] = pp;
        }
        // reduce within the 16-lane group
#pragma unroll
        for (int off = 1; off < 16; off <<= 1) {
#pragma unroll
            for (int hd = 0; hd < 4; hd++)
                part[hd] += __shfl_xor(part[hd], off, 64);
        }

        if (valid) {
#pragma unroll
            for (int hd = 0; hd < 4; hd++) {
                const float sv = part[hd];              // already in log2 units
                const float mn = fmaxf(m[hd], sv);
                const float sc = EXP2(m[hd] - mn);
                const float pp = EXP2(sv - mn);
                l[hd] = l[hd] * sc + pp;
#pragma unroll
                for (int j = 0; j < 8; j++) a[hd][j] = a[hd][j] * sc + pp * hf[j];
                m[hd] = mn;
            }
        }
    }

    // merge the 4 group states (offsets 16, 32)
#pragma unroll
    for (int off = 16; off <= 32; off <<= 1) {
#pragma unroll
        for (int hd = 0; hd < 4; hd++) {
            const float mo = __shfl_xor(m[hd], off, 64);
            const float lo = __shfl_xor(l[hd], off, 64);
            const float mn = fmaxf(m[hd], mo);
            const float sc = EXP2(m[hd] - mn);
            const float so = EXP2(mo - mn);
            l[hd] = l[hd] * sc + lo * so;
#pragma unroll
            for (int j = 0; j < 8; j++) {
                const float ao = __shfl_xor(a[hd][j], off, 64);
                a[hd][j] = a[hd][j] * sc + ao * so;
            }
            m[hd] = mn;
        }
    }

    // group g writes head g (compile-time indices only)
#pragma unroll
    for (int hd = 0; hd < 4; hd++) {
        if (g == hd) {
            const float rl = 1.f / l[hd];
            uint4 o;
            o.x = pack2(a[hd][0] * rl, a[hd][1] * rl);
            o.y = pack2(a[hd][2] * rl, a[hd][3] * rl);
            o.z = pack2(a[hd][4] * rl, a[hd][5] * rl);
            o.w = pack2(a[hd][6] * rl, a[hd][7] * rl);
            *reinterpret_cast<uint4*>(outp) = o;
        }
    }
}

// mail[n] = sum over incoming edges of h[e]; same 4-edge-group structure.
__global__ __launch_bounds__(256) void mail_csr(
    const unsigned short* __restrict__ h,
    const int* __restrict__ rowptr, const int* __restrict__ eidx,
    unsigned short* __restrict__ mailb, int N_)
{
    const int n = blockIdx.x * 4 + (threadIdx.x >> 6);
    if (n >= N_) return;
    const int lane = threadIdx.x & 63;
    const int g = lane >> 4, s = lane & 15;

    const int beg = rowptr[n], end = rowptr[n + 1];

    float a[8];
#pragma unroll
    for (int j = 0; j < 8; j++) a[j] = 0.f;

    const int T = (end - beg + 3) >> 2;
    int idx = beg + g;
    uint4 hv = make_uint4(0u, 0u, 0u, 0u);
    if (idx < end) hv = *reinterpret_cast<const uint4*>(h + (size_t)eidx[idx] * 128 + s * 8);

    for (int it = 0; it < T; it++) {
        const uint4 hc = hv;
        const bool valid = (idx < end);
        const int nidx = idx + 4;
        if (nidx < end) hv = *reinterpret_cast<const uint4*>(h + (size_t)eidx[nidx] * 128 + s * 8);
        idx = nidx;
        if (valid) {
            a[0] += bf2f((unsigned short)(hc.x & 0xffff)); a[1] += bf2f((unsigned short)(hc.x >> 16));
            a[2] += bf2f((unsigned short)(hc.y & 0xffff)); a[3] += bf2f((unsigned short)(hc.y >> 16));
            a[4] += bf2f((unsigned short)(hc.z & 0xffff)); a[5] += bf2f((unsigned short)(hc.z >> 16));
            a[6] += bf2f((unsigned short)(hc.w & 0xffff)); a[7] += bf2f((unsigned short)(hc.w >> 16));
        }
    }
#pragma unroll
    for (int off = 16; off <= 32; off <<= 1)
#pragma unroll
        for (int j = 0; j < 8; j++) a[j] += __shfl_xor(a[j], off, 64);

    if (g == 0) {
        uint4 o;
        o.x = pack2(a[0], a[1]); o.y = pack2(a[2], a[3]);
        o.z = pack2(a[4], a[5]); o.w = pack2(a[6], a[7]);
        *reinterpret_cast<uint4*>(mailb + (size_t)n * 128 + s * 8) = o;
    }
}

// ---------------------------------------------------------------------------
// Precompute kernels
// ---------------------------------------------------------------------------
struct W5 { const float* p[5]; };

__global__ void cvt_wT(W5 w, unsigned short* __restrict__ out) {
    const float* src = w.p[blockIdx.x];
    unsigned short* dst = out + (size_t)blockIdx.x * 16384;
    for (int idx = threadIdx.x; idx < 16384; idx += 256) {
        const int k = idx >> 7, n = idx & 127;
        dst[n * 128 + k] = f2bf(src[idx]);
    }
}

// Score scale folded into Mcat: 1/sqrt(32) * log2(e), so attn uses exp2.
#define SCORE_SCALE 0.25508994161f

// McatT[oc][a] = SC * sum_jj Wq[a][hd*32+jj] * Wk[ip][hd*32+jj]; oc = hd*128+ip
__global__ void mcat_kernel(const float* __restrict__ Wq, const float* __restrict__ Wk,
                            const float* __restrict__ bq,
                            unsigned short* __restrict__ McatT, float* __restrict__ cbias) {
    const int oc = blockIdx.x;            // 0..511
    const int hd = oc >> 7, ip = oc & 127;
    const int a = threadIdx.x;            // 0..127
    const float* wk = Wk + ip * 128 + hd * 32;
    const float* wq = Wq + a * 128 + hd * 32;
    float s = 0.f;
    for (int jj = 0; jj < 32; jj++) s += wq[jj] * wk[jj];
    McatT[(size_t)oc * 128 + a] = f2bf(s * SCORE_SCALE);
    if (a == 0) {
        float c = 0.f;
        for (int jj = 0; jj < 32; jj++) c += bq[hd * 32 + jj] * wk[jj];
        cbias[oc] = c * SCORE_SCALE;
    }
}

// PcatT[j][hd*128+i] = sum_cc Wv[i][hd*32+cc] * Wo[hd*32+cc][j]
__global__ void pcat_kernel(const float* __restrict__ Wv, const float* __restrict__ Wo,
                            unsigned short* __restrict__ PcatT) {
    const int j = blockIdx.x;             // 0..127
    const int k = threadIdx.x;            // 0..511
    const int hd = k >> 7, i = k & 127;
    float s = 0.f;
    for (int cc = 0; cc < 32; cc++)
        s += Wv[i * 128 + hd * 32 + cc] * Wo[(hd * 32 + cc) * 128 + j];
    PcatT[(size_t)j * 512 + k] = f2bf(s);
}

// bias2[j] = sum_c bv[c]*Wo[c][j] + bo[j]
__global__ void bias2_kernel(const float* __restrict__ bv, const float* __restrict__ Wo,
                             const float* __restrict__ bo, float* __restrict__ bias2) {
    const int j = threadIdx.x;
    if (j >= 128) return;
    float s = 0.f;
    for (int c = 0; c < 128; c++) s += bv[c] * Wo[c * 128 + j];
    bias2[j] = s + bo[j];
}

__global__ void cvt_bf16(const float* __restrict__ in, unsigned short* __restrict__ out, long n4) {
    long i = (long)blockIdx.x * 256 + threadIdx.x;
    if (i >= n4) return;
    float4 v = reinterpret_cast<const float4*>(in)[i];
    ushort4 o;
    o.x = f2bf(v.x); o.y = f2bf(v.y); o.z = f2bf(v.z); o.w = f2bf(v.w);
    reinterpret_cast<ushort4*>(out)[i] = o;
}

__global__ void prep_f(const float* __restrict__ f, unsigned short* __restrict__ fb,
                       float* __restrict__ f_h, int n4) {
    int i = blockIdx.x * 256 + threadIdx.x;
    if (i >= n4) return;
    float4 v = reinterpret_cast<const float4*>(f)[i];
    reinterpret_cast<float4*>(f_h)[i] = v;
    ushort4 o;
    o.x = f2bf(v.x); o.y = f2bf(v.y); o.z = f2bf(v.z); o.w = f2bf(v.w);
    reinterpret_cast<ushort4*>(fb)[i] = o;
}

// ---------------------------------------------------------------------------
extern "C" void kernel_launch(void* const* d_in, const int* in_sizes, int n_in,
                              void* d_out, int out_size, void* d_ws, size_t ws_size,
                              hipStream_t stream)
{
    const float* f      = (const float*)d_in[0];
    const float* x      = (const float*)d_in[1];
    const int*   src    = (const int*)d_in[2];
    const int*   dst    = (const int*)d_in[3];
    const float* Wq     = (const float*)d_in[4];
    const float* bq     = (const float*)d_in[5];
    const float* Wk     = (const float*)d_in[6];
    const float* bk     = (const float*)d_in[7];   // cancels in softmax
    const float* Wv     = (const float*)d_in[8];
    const float* bv     = (const float*)d_in[9];
    const float* Wo     = (const float*)d_in[10];
    const float* bo     = (const float*)d_in[11];
    const float* W_mp   = (const float*)d_in[12];
    const float* b_mp   = (const float*)d_in[13];
    const float* W_last = (const float*)d_in[14];
    const float* b_last = (const float*)d_in[15];
    (void)bk;

    const int N = in_sizes[0] / 128;
    const int E = in_sizes[1] / 128;

    char* p = (char*)d_ws;
    auto take = [&](size_t bytes) { char* r = p; p += (bytes + 255) & ~(size_t)255; return r; };
    unsigned short* w5T   = (unsigned short*)take(5 * 16384 * 2);
    unsigned short* McatT = (unsigned short*)take(512 * 128 * 2);
    unsigned short* PcatT = (unsigned short*)take(128 * 512 * 2);
    float* cbias  = (float*)take(512 * 4);
    float* bias2  = (float*)take(128 * 4);
    unsigned short* xb    = (unsigned short*)take((size_t)E * 128 * 2);
    unsigned short* h1    = (unsigned short*)take((size_t)E * 128 * 2);
    unsigned short* h2    = (unsigned short*)take((size_t)E * 128 * 2);
    unsigned short* fb    = (unsigned short*)take((size_t)N * 128 * 2);
    unsigned short* f_hb  = (unsigned short*)take((size_t)N * 128 * 2);
    unsigned short* qkt   = (unsigned short*)take((size_t)N * 512 * 2);
    unsigned short* whm   = (unsigned short*)take((size_t)N * 512 * 2);
    unsigned short* mailb = (unsigned short*)take((size_t)N * 128 * 2);
    float* f_h    = (float*)take((size_t)N * 128 * 4);
    int* deg      = (int*)take((size_t)N * 4);
    int* rowptr   = (int*)take((size_t)(N + 1) * 4);
    int* cursor   = (int*)take((size_t)N * 4);
    int* eidx     = (int*)take((size_t)E * 4);

    const unsigned short* Wm0T = w5T + 0 * 16384;
    const unsigned short* Wm1T = w5T + 1 * 16384;
    const unsigned short* WL0T = w5T + 2 * 16384;
    const unsigned short* WL1T = w5T + 3 * 16384;
    const unsigned short* WL2T = w5T + 4 * 16384;

    W5 w5;
    w5.p[0] = W_mp; w5.p[1] = W_mp + 16384;
    w5.p[2] = W_last; w5.p[3] = W_last + 16384; w5.p[4] = W_last + 32768;

    // --- setup: weights, folded matrices, bf16 copies, CSR ---
    cvt_wT<<<5, 256, 0, stream>>>(w5, w5T);
    mcat_kernel<<<512, 128, 0, stream>>>(Wq, Wk, bq, McatT, cbias);
    pcat_kernel<<<128, 512, 0, stream>>>(Wv, Wo, PcatT);
    bias2_kernel<<<1, 128, 0, stream>>>(bv, Wo, bo, bias2);
    cvt_bf16<<<(int)(((long)E * 32 + 255) / 256), 256, 0, stream>>>(x, xb, (long)E * 32);
    prep_f<<<(N * 32 + 255) / 256, 256, 0, stream>>>(f, fb, f_h, N * 32);

    hipMemsetAsync(deg, 0, (size_t)N * 4, stream);
    hist_kernel<<<(E + 255) / 256, 256, 0, stream>>>(dst, deg, E);
    scan_kernel<<<1, 1024, 0, stream>>>(deg, rowptr, cursor, N);
    scatter_kernel<<<(E + 255) / 256, 256, 0, stream>>>(dst, cursor, eidx, E);

    const int ntN = (N + 63) / 64;
    const int ntE = (E + 63) / 64;
    const int gNode = (N + 3) / 4;

    const unsigned short* hc = xb;
    unsigned short* houts[2] = { h1, h2 };
    for (int it = 0; it < 2; it++) {
        const unsigned short* fh_in = (it == 0) ? fb : f_hb;
        // qkt = f_h @ Mcat + c   (bf16 [N,512], log2-scaled scores)
        gemm_q512<<<ntN, 512, 0, stream>>>(fh_in, McatT, cbias, qkt, N);
        // fused attention -> normalized weighted mailbox whm (bf16 [N,512])
        attn_fused<<<gNode, 256, 0, stream>>>(qkt, hc, rowptr, eidx, whm, N);
        // f_h += whm @ Pcat + bias2 ; f_hb = bf16(f_h)
        gemm_k512<<<ntN, 256, 0, stream>>>(whm, PcatT, bias2, f_h, f_hb, N);
        // h' = relu(x + (f_hb[src] - rev(h)) @ Wm + b)
        gemm_mrelu<<<768, 256, 0, stream>>>(
            f_hb, hc, src, (it == 0) ? Wm0T : Wm1T, b_mp + (size_t)it * 128,
            xb, houts[it], E, ntE);
        hc = houts[it];
    }

    // mail = segment_sum(h, dst)
    mail_csr<<<gNode, 256, 0, stream>>>(hc, rowptr, eidx, mailb, N);

    // out = mail@WL0 + f_h@WL1 + f@WL2 + b_last
    gemm_s<0, false, false><<<ntN, 256, 0, stream>>>(
        mailb, WL0T, b_last, nullptr, (float*)d_out, nullptr, N, ntN);
    gemm_s<1, false, false><<<ntN, 256, 0, stream>>>(
        f_hb, WL1T, nullptr, d_out, (float*)d_out, nullptr, N, ntN);
    gemm_s<1, false, false><<<ntN, 256, 0, stream>>>(
        fb, WL2T, nullptr, d_out, (float*)d_out, nullptr, N, ntN);
}